// Round 2
// baseline (572.388 us; speedup 1.0000x reference)
//
#include <hip/hip_runtime.h>
#include <hip/hip_bf16.h>
#include <hip/hip_fp16.h>
#include <cstdint>
#include <cstddef>

typedef unsigned short u16;
typedef __attribute__((ext_vector_type(8))) short bf16x8;
typedef __attribute__((ext_vector_type(4))) float f32x4;

#define MFMA16(a,b,c) __builtin_amdgcn_mfma_f32_16x16x32_bf16((a),(b),(c),0,0,0)

// B=2 T=16 H=W=56 C=128  HW=3136  N=100352  HID=512
// GP/HP (f16) layout: [b][cg32][hw3136][cl4][t16]  (t contiguous, 32B per (hw,cl))
//   u16 idx = (((b*32+cg)*3136 + hw)*4 + cl)*16 + t          slab = 200704 u16/(b,cg)
// ELH (bf16) layout: (((b*32+cg)*16 + t)*3136 + hw)*4 + cl

static __device__ __forceinline__ float b2f(u16 u){ return __uint_as_float(((unsigned)u)<<16); }
static __device__ __forceinline__ u16 f2b(float f){
  unsigned u = __float_as_uint(f);
  return (u16)((u + 0x7fffu + ((u>>16)&1u)) >> 16);
}
static __device__ __forceinline__ u16 f2h(float f){ return __half_as_ushort(__float2half(f)); }
static __device__ __forceinline__ __half2 u2h(unsigned u){ union{unsigned u;__half2 h;}c; c.u=u; return c.h; }

// async global->LDS 16B: LDS dest = wave-uniform base + lane*16, global src per-lane
static __device__ __forceinline__ void gld_lds16(const void* g, void* l){
  __builtin_amdgcn_global_load_lds(
      (const __attribute__((address_space(1))) void*)g,
      (__attribute__((address_space(3))) void*)l, 16, 0, 0);
}

// dtype detector: sample 64 even-index u16 words of x. bf16 N(0,1) data -> exponent
// field in [100,140] essentially always; f32 -> mantissa halves, ~uniform exponent.
static __device__ __forceinline__ bool input_is_f32(const void* xp){
  const u16* u = (const u16*)xp;
  int cnt = 0;
#pragma unroll
  for (int i = 0; i < 64; ++i){
    unsigned e = (u[2*i] >> 7) & 0xFF;
    cnt += (e >= 100 && e <= 140) ? 1 : 0;
  }
  return cnt < 32;
}

static __device__ __forceinline__ u16 ldb(const void* p, int i, bool f32){
  return f32 ? f2b(((const float*)p)[i]) : ((const u16*)p)[i];
}
static __device__ __forceinline__ float ldf(const void* p, int i, bool f32){
  return f32 ? ((const float*)p)[i] : b2f(((const u16*)p)[i]);
}

// ---------------- K0: canonicalize inputs (+ transposes + conv f16 pair relayout) ----------------
__global__ __launch_bounds__(256) void k0_prep(
    const void* __restrict__ x,
    const void* __restrict__ Wg, const void* __restrict__ Wh, const void* __restrict__ Wo,
    const void* __restrict__ W1, const void* __restrict__ W2,
    const void* __restrict__ gk, const void* __restrict__ hk,
    const void* __restrict__ bg, const void* __restrict__ bh, const void* __restrict__ bo,
    const void* __restrict__ lns, const void* __restrict__ lnb,
    const void* __restrict__ b1, const void* __restrict__ b2, const void* __restrict__ gm,
    u16* __restrict__ XB,
    u16* __restrict__ WgT, u16* __restrict__ WhT, u16* __restrict__ WoT,
    u16* __restrict__ W1T, u16* __restrict__ W2T,
    unsigned* __restrict__ KWG, unsigned* __restrict__ KWH, u16* __restrict__ PRM)
{
  const bool f32 = input_is_f32(x);
  int tid = blockIdx.x*blockDim.x + threadIdx.x;
  int np  = gridDim.x*blockDim.x;

  // x -> XB (bf16), 2 elements per u32 store
  if (f32){
    const float* xf = (const float*)x;
    for (int p = tid; p < 6422528; p += np){
      unsigned v = (unsigned)f2b(xf[2*p]) | ((unsigned)f2b(xf[2*p+1]) << 16);
      ((unsigned*)XB)[p] = v;
    }
  } else {
    const unsigned* xu = (const unsigned*)x;
    for (int p = tid; p < 6422528; p += np) ((unsigned*)XB)[p] = xu[p];
  }

  for (int p = tid; p < 16384; p += np){           // 128x128 transposes
    int n = p>>7, k = p&127;
    WgT[p] = ldb(Wg, k*128+n, f32);
    WhT[p] = ldb(Wh, k*128+n, f32);
    WoT[p] = ldb(Wo, k*128+n, f32);
  }
  for (int p = tid; p < 65536; p += np){           // W1 (128,512) -> W1T (512,128)
    int n = p>>7, k = p&127;
    W1T[p] = ldb(W1, k*512+n, f32);
  }
  for (int p = tid; p < 65536; p += np){           // W2 (512,128) -> W2T (128,512)
    int n = p>>9, k = p&511;
    W2T[p] = ldb(W2, k*128+n, f32);
  }
  // conv kernels: [jk49][c128][tap8] u32, each u32 = f16 weight duplicated (w,w); tap>=5 zero
  for (int p = tid; p < 50176; p += np){
    int tap = p&7, c = (p>>3)&127, jk = p>>10;
    unsigned vg = 0, vh = 0;
    if (tap < 5){
      int s = (c*5+tap)*49 + jk;
      unsigned g16 = f2h(ldf(gk, s, f32)), h16 = f2h(ldf(hk, s, f32));
      vg = g16 | (g16<<16); vh = h16 | (h16<<16);
    }
    KWG[p] = vg; KWH[p] = vh;
  }
  // param block (bf16): bg@0 bh@128 bo@256 lns@384 lnb@512 b1@640 b2@1152 gamma@1280
  for (int p = tid; p < 1408; p += np){
    const void* src; int off;
    if      (p < 128)  { src = bg;  off = p; }
    else if (p < 256)  { src = bh;  off = p-128; }
    else if (p < 384)  { src = bo;  off = p-256; }
    else if (p < 512)  { src = lns; off = p-384; }
    else if (p < 640)  { src = lnb; off = p-512; }
    else if (p < 1152) { src = b1;  off = p-640; }
    else if (p < 1280) { src = b2;  off = p-1152; }
    else               { src = gm;  off = p-1280; }
    PRM[p] = ldb(src, off, f32);
  }
}

// ---------------- K1: dual GEMM  gate = x@Wg+bg, hidden = x@Wh+bh (f16 out, t-contiguous) ----------------
__global__ __launch_bounds__(256) void k1_dualgemm(
    const u16* __restrict__ XB, const u16* __restrict__ WgT, const u16* __restrict__ WhT,
    const u16* __restrict__ PRM,
    u16* __restrict__ GP, u16* __restrict__ HP)
{
  int bid = blockIdx.x;                  // 1568 = 2b * 784 hw-groups
  int b = bid / 784; int hw = (bid % 784)*4 + (threadIdx.x >> 6);
  int lane = threadIdx.x & 63;
  int lrow = lane & 15, q = lane >> 4;

  bf16x8 a[4];   // A row (in-tile) = lrow = t; k-cols q*8 + kt*32
  const u16* xr = XB + ((size_t)(b*16 + lrow)*3136 + hw)*128 + q*8;
#pragma unroll
  for (int kt = 0; kt < 4; ++kt) a[kt] = *(const bf16x8*)(xr + kt*32);

#pragma unroll
  for (int mat = 0; mat < 2; ++mat){
    const u16* WT  = mat ? WhT : WgT;
    const u16* bia = PRM + (mat ? 128 : 0);
    u16* out       = mat ? HP  : GP;
#pragma unroll
    for (int nt = 0; nt < 8; ++nt){
      f32x4 acc = {0.f,0.f,0.f,0.f};
      const u16* wr = WT + (nt*16 + lrow)*128 + q*8;
#pragma unroll
      for (int kt = 0; kt < 4; ++kt){
        bf16x8 bfr = *(const bf16x8*)(wr + kt*32);
        acc = MFMA16(a[kt], bfr, acc);
      }
      int c = nt*16 + lrow;              // C col = output channel
      float bv = b2f(bia[c]);
      size_t base = (((size_t)(b*32 + (c>>2))*3136 + hw)*4 + (c&3))*16 + q*4;
      ushort4 pk;
      pk.x = f2h(acc[0] + bv); pk.y = f2h(acc[1] + bv);
      pk.z = f2h(acc[2] + bv); pk.w = f2h(acc[3] + bv);
      *(ushort4*)(out + base) = pk;      // t = q*4 .. q*4+3
    }
  }
}

// ---------------- K2: circular 5x7x7 depthwise conv (packed f16), two-pass LDS, + scan ----------------
__global__ __launch_bounds__(256, 5) void k2_conv_scan(
    const u16* __restrict__ GP, const u16* __restrict__ HP,
    const unsigned* __restrict__ KWG, const unsigned* __restrict__ KWH,
    u16* __restrict__ ELH)
{
  __shared__ __align__(16) unsigned su[6272];
  __shared__ __align__(16) unsigned ku[1568];    // [jk49][cl4][tap8] (w,w) f16 pairs

  int bid = blockIdx.x;                    // 3136 = 2 * 32 * 49
  int b = bid / 1568; int rr = bid - b*1568;
  int cg = rr / 49; int s = rr % 49;
  int th = s / 7, tw = s % 7;
  int tid = threadIdx.x;
  int h0g = th*8, w0g = tw*8;
  size_t tb = (size_t)(b*32 + cg)*200704;  // u16 slab base (GP/HP/ELH identical value)

  int cl = tid & 3, w0 = (tid>>2)&7, h0 = tid>>5;
  int wv = tid >> 6, lane = tid & 63;

  // ---- precompute per-thread staging chunk offsets (reused: 2 halves x 2 passes) ----
  unsigned soff[4]; bool sval[4];
#pragma unroll
  for (int ss = 0; ss < 4; ++ss){
    int idx = wv*64 + ss*256 + lane;
    sval[ss] = (idx < 784);
    int pos = idx >> 2, pcl = idx & 3;
    int hh = pos / 14, ww = pos - hh*14;
    int hg = h0g + hh - 3; if (hg < 0) hg += 56; else if (hg >= 56) hg -= 56;
    int wg = w0g + ww - 3; if (wg < 0) wg += 56; else if (wg >= 56) wg -= 56;
    soff[ss] = (unsigned)(((hg*56 + wg)*4 + pcl)*32);   // byte offset within slab
  }
  const char* gpb = (const char*)(GP + tb);
  const char* hpb = (const char*)(HP + tb);

  auto wload = [&](const unsigned* KW){
    for (int p = tid; p < 1568; p += 256){
      int tap = p & 7, c2 = (p>>3)&3, jk = p>>5;
      ku[p] = KW[(jk*128 + cg*4 + c2)*8 + tap];
    }
  };
  auto stagepass = [&](const char* Pb){
#pragma unroll
    for (int half = 0; half < 2; ++half){
#pragma unroll
      for (int ss = 0; ss < 4; ++ss){
        if (sval[ss])
          gld_lds16(Pb + soff[ss] + half*16,
                    (char*)su + half*12544 + (wv*64 + ss*256)*16);
      }
    }
  };
  auto convpass = [&](__half2* A){
#pragma unroll
    for (int p = 0; p < 8; ++p) A[p] = u2h(0u);
    for (int j = 0; j < 7; ++j){
      int hh = h0 + 6 - j;
      int cb0 = ((hh*14 + w0)*4 + cl)*4;     // u32 index at k=6
      int wb0 = (j*28 + cl)*8;               // u32 index at k=0
#pragma unroll
      for (int k = 0; k < 7; ++k){
        const unsigned* sp = &su[cb0 + (6-k)*16];
        uint4 da = *(const uint4*)sp;
        uint4 db = *(const uint4*)(sp + 3136);
        unsigned P[8] = {da.x,da.y,da.z,da.w,db.x,db.y,db.z,db.w};
        unsigned M[8];
#pragma unroll
        for (int p = 0; p < 8; ++p) M[p] = (P[p]>>16) | (P[(p+1)&7]<<16);
        const unsigned* kp = &ku[wb0 + k*32];
        uint4 w4 = *(const uint4*)kp;
        unsigned w5 = kp[4];
        // out[t] += sum_i w[i] * X[(t-i+2)&15]
#pragma unroll
        for (int p = 0; p < 8; ++p){
          A[p] = __hfma2(u2h(w4.x), u2h(P[(p+1)&7]), A[p]);   // i=0: X[t+2]
          A[p] = __hfma2(u2h(w4.y), u2h(M[p]),       A[p]);   // i=1: X[t+1]
          A[p] = __hfma2(u2h(w4.z), u2h(P[p]),       A[p]);   // i=2: X[t]
          A[p] = __hfma2(u2h(w4.w), u2h(M[(p+7)&7]), A[p]);   // i=3: X[t-1]
          A[p] = __hfma2(u2h(w5),   u2h(P[(p+7)&7]), A[p]);   // i=4: X[t-2]
        }
      }
    }
  };

  __half2 Ag[8], Ah[8];
  wload(KWG);
  stagepass(gpb);
  __syncthreads();          // drains vmcnt: global_load_lds data resident
  convpass(Ag);
  __syncthreads();          // conv reads done before restage overwrites
  wload(KWH);
  stagepass(hpb);
  __syncthreads();
  convpass(Ah);

  float xg[16], xh[16];
#pragma unroll
  for (int p = 0; p < 8; ++p){
    float2 g2 = __half22float2(Ag[p]); xg[2*p] = g2.x; xg[2*p+1] = g2.y;
    float2 h2 = __half22float2(Ah[p]); xh[2*p] = h2.x; xh[2*p+1] = h2.y;
  }

  // pointwise + scan over T + store exp(log_h) (bf16)
  size_t ob = tb + ((size_t)(h0g + h0)*56 + (w0g + w0))*4 + cl;
  float lh = 0.f;
#pragma unroll
  for (int t = 0; t < 16; ++t){
    float g  = xg[t];
    float spg = fmaxf(g, 0.f) + __logf(1.f + __expf(-fabsf(g)));  // softplus(g)
    float lf  = -spg;                                             // log(1-z)
    float hv  = xh[t];
    float lv  = (g - spg) + __logf(hv*hv + 1e-6f);                // log z + log h~^2
    if (t == 0) lh = lv;
    else {
      float a_ = lf + lh;
      float mx = fmaxf(a_, lv);
      lh = mx + __logf(1.f + __expf(-fabsf(a_ - lv)));
    }
    ELH[ob + (size_t)t*12544] = f2b(__expf(lh));
  }
}

// ---------------- K34: (elh@Wo+bo) -> LayerNorm -> MLP -> gamma*y + residual, fused ----------------
// Phase A (k3): GEMM+LN into LDS tile sX (64 x 136, aligned rows).
// Phase B (k4): A-frags from sX (same-wave); nt-loop with REGISTER-double-buffered W tiles:
//   nt+1's global loads issued right after nt's ds_write, in flight across raw s_barrier
//   (no __syncthreads: its implicit vmcnt(0) drain would serialize the prefetch).
__global__ __launch_bounds__(256) void k34_gemm_ln_mlp(
    const u16* __restrict__ ELH, const u16* __restrict__ WoT,
    const u16* __restrict__ W1T, const u16* __restrict__ W2T,
    const u16* __restrict__ PRM,
    const void* __restrict__ xraw, void* __restrict__ outv)
{
  __shared__ __align__(16) u16 smem[20992];   // 41,984 B
  u16* sX = smem;            // 64*136 = 8704 u16 (phase A)
  u16* sW = smem;            // 16384 u16 (phase B, aliases sX after barrier)
  u16* sH = smem + 16384;    // 4*16*72 = 4608 u16

  int bid = blockIdx.x;                 // 1568 * 64 rows
  int b = bid / 784; int t = (bid % 784) / 49; int hw0 = (bid % 49) * 64;
  int n0 = bid * 64;
  int tid = threadIdx.x;
  int wv = tid >> 6, lane = tid & 63;
  int lrow = lane & 15, q = lane >> 4;
  const bool f32io = input_is_f32(xraw);

  // ---- phase A: ssm_out = elh@Wo + bo, LayerNorm -> sX ----
  {
    int hw = hw0 + wv*16 + lrow;
    size_t tbase = ((size_t)(b*32)*16 + t)*3136;
    union Cvt { uint4 u; bf16x8 v; };
    bf16x8 a[4];
#pragma unroll
    for (int kt = 0; kt < 4; ++kt){
      int cg0 = kt*8 + q*2;
      size_t e0 = (tbase + (size_t)cg0*50176 + hw)*4;
      uint2 lo = *(const uint2*)(ELH + e0);
      uint2 hi = *(const uint2*)(ELH + e0 + (size_t)50176*4);
      Cvt cvt; cvt.u = make_uint4(lo.x, lo.y, hi.x, hi.y);
      a[kt] = cvt.v;
    }

    float vals[8][4];
#pragma unroll
    for (int nt = 0; nt < 8; ++nt){
      f32x4 acc = {0.f,0.f,0.f,0.f};
      const u16* wr = WoT + (nt*16 + lrow)*128 + q*8;
#pragma unroll
      for (int kt = 0; kt < 4; ++kt){
        bf16x8 bfr = *(const bf16x8*)(wr + kt*32);
        acc = MFMA16(a[kt], bfr, acc);
      }
      float bv = b2f(PRM[256 + nt*16 + lrow]);
#pragma unroll
      for (int i = 0; i < 4; ++i) vals[nt][i] = acc[i] + bv;
    }

#pragma unroll
    for (int i = 0; i < 4; ++i){
      float sm = 0.f, sq = 0.f;
#pragma unroll
      for (int nt = 0; nt < 8; ++nt){ float v = vals[nt][i]; sm += v; sq = fmaf(v, v, sq); }
#pragma unroll
      for (int m = 1; m < 16; m <<= 1){ sm += __shfl_xor(sm, m, 64); sq += __shfl_xor(sq, m, 64); }
      float mean = sm * (1.f/128.f);
      float var  = sq * (1.f/128.f) - mean*mean;
      float rstd = rsqrtf(var + 1e-6f);
      int r = wv*16 + q*4 + i;
#pragma unroll
      for (int nt = 0; nt < 8; ++nt){
        int c = nt*16 + lrow;
        float xn = (vals[nt][i] - mean)*rstd*b2f(PRM[384 + c]) + b2f(PRM[512 + c]);
        sX[r*136 + c] = f2b(xn);
      }
    }
  }

  // ---- phase B: MLP. A-frags from sX (written by this same wave -> no barrier needed) ----
  bf16x8 a[4];
#pragma unroll
  for (int kt = 0; kt < 4; ++kt)
    a[kt] = *(const bf16x8*)&sX[(wv*16 + lrow)*136 + kt*32 + q*8];

  f32x4 acc[8];
#pragma unroll
  for (int jo = 0; jo < 8; ++jo) acc[jo] = (f32x4){0.f,0.f,0.f,0.f};

  u16* sHw = sH + wv*1152;

  // per-thread W-tile source addresses (nt-dependent part is a constant stride)
  const u16* wsrc0[8];
#pragma unroll
  for (int r = 0; r < 8; ++r){
    int c = r*4 + wv;
    if (c < 16){
      int j = c >> 2, kt = c & 3;
      wsrc0[r] = W1T + (size_t)(j*16 + lrow)*128 + kt*32 + q*8;   // + nt*64*128
    } else {
      int c2 = c - 16; int jo = c2 >> 1, kt2 = c2 & 1;
      wsrc0[r] = W2T + (size_t)(jo*16 + lrow)*512 + kt2*32 + q*8; // + nt*64
    }
  }
  auto wadv = [&](int r, int nt) -> const u16* {
    int c = r*4 + wv;
    return wsrc0[r] + (c < 16 ? (size_t)nt*64*128 : (size_t)nt*64);
  };

  // prologue: issue W(0) loads (fly under nothing; first iter pays latency once)
  uint4 wreg[8];
#pragma unroll
  for (int r = 0; r < 8; ++r) wreg[r] = *(const uint4*)wadv(r, 0);

  for (int nt = 0; nt < 8; ++nt){
    // barrier A: all waves done reading sW (prev iter) / sX (iter 0).
    asm volatile("s_waitcnt lgkmcnt(0)" ::: "memory");
    __builtin_amdgcn_s_barrier();
    // write current W tile (compiler waits vmcnt for wreg here; loads are old -> ~free)
#pragma unroll
    for (int r = 0; r < 8; ++r)
      *(uint4*)&sW[(r*4 + wv)*512 + lane*8] = wreg[r];
    // issue next tile's loads NOW: they stay in flight across the barrier + compute
    if (nt < 7){
#pragma unroll
      for (int r = 0; r < 8; ++r) wreg[r] = *(const uint4*)wadv(r, nt+1);
    }
    // barrier B: sW visible to all (lgkmcnt(0) only -- vmcnt deliberately NOT drained)
    asm volatile("s_waitcnt lgkmcnt(0)" ::: "memory");
    __builtin_amdgcn_s_barrier();

    // ---- phase 1: H-tile = gelu(XN @ W1tile + b1) -> per-wave LDS scratch ----
#pragma unroll
    for (int js = 0; js < 4; ++js){
      f32x4 hc = {0.f,0.f,0.f,0.f};
#pragma unroll
      for (int kt = 0; kt < 4; ++kt){
        bf16x8 bfr = *(const bf16x8*)&sW[(js*4 + kt)*512 + lane*8];
        hc = MFMA16(a[kt], bfr, hc);
      }
      float bv = b2f(PRM[640 + nt*64 + js*16 + lrow]);
#pragma unroll
      for (int i = 0; i < 4; ++i){
        float v = hc[i] + bv;
        float u = 0.79788456080286535588f*(v + 0.044715f*v*v*v);
        float s = __expf(-2.f*u);
        float gl = v * __builtin_amdgcn_rcpf(1.f + s);        // v * sigmoid(2u)
        sHw[(q*4 + i)*72 + js*16 + lrow] = (u16)(__float_as_uint(gl) >> 16);
      }
    }
    // ---- phase 2: acc += H-tile @ W2tile (A-frags from scratch, same wave, in-order DS) ----
#pragma unroll
    for (int kt2 = 0; kt2 < 2; ++kt2){
      bf16x8 af = *(const bf16x8*)&sHw[lrow*72 + kt2*32 + q*8];
#pragma unroll
      for (int jo = 0; jo < 8; ++jo){
        bf16x8 bfr = *(const bf16x8*)&sW[(16 + jo*2 + kt2)*512 + lane*8];
        acc[jo] = MFMA16(af, bfr, acc[jo]);
      }
    }
  }

  // ---- epilogue: out = (acc + b2)*gamma + x ----
#pragma unroll
  for (int jo = 0; jo < 8; ++jo){
    int c = jo*16 + lrow;
    float bv  = b2f(PRM[1152 + c]);
    float gmv = b2f(PRM[1280 + c]);
#pragma unroll
    for (int i = 0; i < 4; ++i){
      size_t row = (size_t)(n0 + wv*16 + q*4 + i);
      float y = acc[jo][i] + bv;
      float res = f32io ? ((const float*)xraw)[row*128 + c]
                        : b2f(((const u16*)xraw)[row*128 + c]);
      float o = y*gmv + res;
      if (f32io) ((float*)outv)[row*128 + c] = o;
      else       ((u16*) outv)[row*128 + c] = f2b(o);
    }
  }
}

// ---------------- launch ----------------
extern "C" void kernel_launch(void* const* d_in, const int* in_sizes, int n_in,
                              void* d_out, int out_size, void* d_ws, size_t ws_size,
                              hipStream_t stream)
{
  const void* x   = d_in[0];
  const void* Wg  = d_in[1];
  const void* bg  = d_in[2];
  const void* Wh  = d_in[3];
  const void* bh  = d_in[4];
  const void* gk  = d_in[5];
  const void* hk  = d_in[6];
  const void* Wo  = d_in[7];
  const void* bo  = d_in[8];
  const void* lns = d_in[9];
  const void* lnb = d_in[10];
  const void* W1  = d_in[11];
  const void* b1  = d_in[12];
  const void* W2  = d_in[13];
  const void* b2  = d_in[14];
  const void* gm  = d_in[15];

  char* ws = (char*)d_ws;
  u16* GP  = (u16*)(ws + 0);              // 25,690,112 B each (f16)
  u16* HP  = (u16*)(ws + 25690112);
  u16* ELH = (u16*)(ws + 51380224);       // bf16
  u16* XB  = (u16*)(ws + 77070336);       // canonical bf16 x
  u16* WgT = (u16*)(ws + 102760448);
  u16* WhT = WgT + 16384;
  u16* WoT = WhT + 16384;
  u16* W1T = WoT + 16384;
  u16* W2T = W1T + 65536;
  unsigned* KWG = (unsigned*)(W2T + 65536);    // 50,176 u32 each
  unsigned* KWH = KWG + 50176;
  u16* PRM = (u16*)(KWH + 50176);

  k0_prep        <<<dim3(512),  dim3(256), 0, stream>>>(x, Wg, Wh, Wo, W1, W2, gk, hk,
                                                        bg, bh, bo, lns, lnb, b1, b2, gm,
                                                        XB, WgT, WhT, WoT, W1T, W2T, KWG, KWH, PRM);
  k1_dualgemm    <<<dim3(1568), dim3(256), 0, stream>>>(XB, WgT, WhT, PRM, GP, HP);
  k2_conv_scan   <<<dim3(3136), dim3(256), 0, stream>>>(GP, HP, KWG, KWH, ELH);
  k34_gemm_ln_mlp<<<dim3(1568), dim3(256), 0, stream>>>(ELH, WoT, W1T, W2T, PRM, x, (void*)d_out);
}

// Round 3
// 453.610 us; speedup vs baseline: 1.2618x; 1.2618x over previous
//
#include <hip/hip_runtime.h>
#include <hip/hip_bf16.h>
#include <hip/hip_fp16.h>
#include <cstdint>
#include <cstddef>

typedef unsigned short u16;
typedef __attribute__((ext_vector_type(8))) short bf16x8;
typedef __attribute__((ext_vector_type(4))) float f32x4;

#define MFMA16(a,b,c) __builtin_amdgcn_mfma_f32_16x16x32_bf16((a),(b),(c),0,0,0)

// B=2 T=16 H=W=56 C=128  HW=3136  N=100352  HID=512
// GP/HP (f16) layout: [b][cg32][hw3136][cl4][t16]  (t contiguous, 32B per (hw,cl))
//   u16 idx = (((b*32+cg)*3136 + hw)*4 + cl)*16 + t          slab = 200704 u16/(b,cg)
// ELH (bf16) layout: (((b*32+cg)*16 + t)*3136 + hw)*4 + cl

static __device__ __forceinline__ float b2f(u16 u){ return __uint_as_float(((unsigned)u)<<16); }
static __device__ __forceinline__ u16 f2b(float f){
  unsigned u = __float_as_uint(f);
  return (u16)((u + 0x7fffu + ((u>>16)&1u)) >> 16);
}
static __device__ __forceinline__ u16 f2h(float f){ return __half_as_ushort(__float2half(f)); }
static __device__ __forceinline__ __half2 u2h(unsigned u){ union{unsigned u;__half2 h;}c; c.u=u; return c.h; }

// async global->LDS 16B: LDS dest = wave-uniform base + lane*16, global src per-lane
static __device__ __forceinline__ void gld_lds16(const void* g, void* l){
  __builtin_amdgcn_global_load_lds(
      (const __attribute__((address_space(1))) void*)g,
      (__attribute__((address_space(3))) void*)l, 16, 0, 0);
}

// dtype detector: sample 64 even-index u16 words of x. bf16 N(0,1) data -> exponent
// field in [100,140] essentially always; f32 -> mantissa halves, ~uniform exponent.
static __device__ __forceinline__ bool input_is_f32(const void* xp){
  const u16* u = (const u16*)xp;
  int cnt = 0;
#pragma unroll
  for (int i = 0; i < 64; ++i){
    unsigned e = (u[2*i] >> 7) & 0xFF;
    cnt += (e >= 100 && e <= 140) ? 1 : 0;
  }
  return cnt < 32;
}

static __device__ __forceinline__ u16 ldb(const void* p, int i, bool f32){
  return f32 ? f2b(((const float*)p)[i]) : ((const u16*)p)[i];
}
static __device__ __forceinline__ float ldf(const void* p, int i, bool f32){
  return f32 ? ((const float*)p)[i] : b2f(((const u16*)p)[i]);
}

// ---------------- K0: canonicalize inputs (+ transposes + conv f16 pair relayout) ----------------
__global__ __launch_bounds__(256) void k0_prep(
    const void* __restrict__ x,
    const void* __restrict__ Wg, const void* __restrict__ Wh, const void* __restrict__ Wo,
    const void* __restrict__ W1, const void* __restrict__ W2,
    const void* __restrict__ gk, const void* __restrict__ hk,
    const void* __restrict__ bg, const void* __restrict__ bh, const void* __restrict__ bo,
    const void* __restrict__ lns, const void* __restrict__ lnb,
    const void* __restrict__ b1, const void* __restrict__ b2, const void* __restrict__ gm,
    u16* __restrict__ XB,
    u16* __restrict__ WgT, u16* __restrict__ WhT, u16* __restrict__ WoT,
    u16* __restrict__ W1T, u16* __restrict__ W2T,
    unsigned* __restrict__ KWG, unsigned* __restrict__ KWH, u16* __restrict__ PRM)
{
  const bool f32 = input_is_f32(x);
  int tid = blockIdx.x*blockDim.x + threadIdx.x;
  int np  = gridDim.x*blockDim.x;

  // x -> XB (bf16), 2 elements per u32 store
  if (f32){
    const float* xf = (const float*)x;
    for (int p = tid; p < 6422528; p += np){
      unsigned v = (unsigned)f2b(xf[2*p]) | ((unsigned)f2b(xf[2*p+1]) << 16);
      ((unsigned*)XB)[p] = v;
    }
  } else {
    const unsigned* xu = (const unsigned*)x;
    for (int p = tid; p < 6422528; p += np) ((unsigned*)XB)[p] = xu[p];
  }

  for (int p = tid; p < 16384; p += np){           // 128x128 transposes
    int n = p>>7, k = p&127;
    WgT[p] = ldb(Wg, k*128+n, f32);
    WhT[p] = ldb(Wh, k*128+n, f32);
    WoT[p] = ldb(Wo, k*128+n, f32);
  }
  for (int p = tid; p < 65536; p += np){           // W1 (128,512) -> W1T (512,128)
    int n = p>>7, k = p&127;
    W1T[p] = ldb(W1, k*512+n, f32);
  }
  for (int p = tid; p < 65536; p += np){           // W2 (512,128) -> W2T (128,512)
    int n = p>>9, k = p&511;
    W2T[p] = ldb(W2, k*128+n, f32);
  }
  // conv kernels: [jk49][c128][tap8] u32, each u32 = f16 weight duplicated (w,w); tap>=5 zero
  for (int p = tid; p < 50176; p += np){
    int tap = p&7, c = (p>>3)&127, jk = p>>10;
    unsigned vg = 0, vh = 0;
    if (tap < 5){
      int s = (c*5+tap)*49 + jk;
      unsigned g16 = f2h(ldf(gk, s, f32)), h16 = f2h(ldf(hk, s, f32));
      vg = g16 | (g16<<16); vh = h16 | (h16<<16);
    }
    KWG[p] = vg; KWH[p] = vh;
  }
  // param block (bf16): bg@0 bh@128 bo@256 lns@384 lnb@512 b1@640 b2@1152 gamma@1280
  for (int p = tid; p < 1408; p += np){
    const void* src; int off;
    if      (p < 128)  { src = bg;  off = p; }
    else if (p < 256)  { src = bh;  off = p-128; }
    else if (p < 384)  { src = bo;  off = p-256; }
    else if (p < 512)  { src = lns; off = p-384; }
    else if (p < 640)  { src = lnb; off = p-512; }
    else if (p < 1152) { src = b1;  off = p-640; }
    else if (p < 1280) { src = b2;  off = p-1152; }
    else               { src = gm;  off = p-1280; }
    PRM[p] = ldb(src, off, f32);
  }
}

// ---------------- K1: dual GEMM  gate = x@Wg+bg, hidden = x@Wh+bh (f16 out, t-contiguous) ----------------
__global__ __launch_bounds__(256) void k1_dualgemm(
    const u16* __restrict__ XB, const u16* __restrict__ WgT, const u16* __restrict__ WhT,
    const u16* __restrict__ PRM,
    u16* __restrict__ GP, u16* __restrict__ HP)
{
  int bid = blockIdx.x;                  // 1568 = 2b * 784 hw-groups
  int b = bid / 784; int hw = (bid % 784)*4 + (threadIdx.x >> 6);
  int lane = threadIdx.x & 63;
  int lrow = lane & 15, q = lane >> 4;

  bf16x8 a[4];   // A row (in-tile) = lrow = t; k-cols q*8 + kt*32
  const u16* xr = XB + ((size_t)(b*16 + lrow)*3136 + hw)*128 + q*8;
#pragma unroll
  for (int kt = 0; kt < 4; ++kt) a[kt] = *(const bf16x8*)(xr + kt*32);

#pragma unroll
  for (int mat = 0; mat < 2; ++mat){
    const u16* WT  = mat ? WhT : WgT;
    const u16* bia = PRM + (mat ? 128 : 0);
    u16* out       = mat ? HP  : GP;
#pragma unroll
    for (int nt = 0; nt < 8; ++nt){
      f32x4 acc = {0.f,0.f,0.f,0.f};
      const u16* wr = WT + (nt*16 + lrow)*128 + q*8;
#pragma unroll
      for (int kt = 0; kt < 4; ++kt){
        bf16x8 bfr = *(const bf16x8*)(wr + kt*32);
        acc = MFMA16(a[kt], bfr, acc);
      }
      int c = nt*16 + lrow;              // C col = output channel
      float bv = b2f(bia[c]);
      size_t base = (((size_t)(b*32 + (c>>2))*3136 + hw)*4 + (c&3))*16 + q*4;
      ushort4 pk;
      pk.x = f2h(acc[0] + bv); pk.y = f2h(acc[1] + bv);
      pk.z = f2h(acc[2] + bv); pk.w = f2h(acc[3] + bv);
      *(ushort4*)(out + base) = pk;      // t = q*4 .. q*4+3
    }
  }
}

// ---------------- K2: circular 5x7x7 depthwise conv (packed f16), two-pass LDS, + scan ----------------
__global__ __launch_bounds__(256, 5) void k2_conv_scan(
    const u16* __restrict__ GP, const u16* __restrict__ HP,
    const unsigned* __restrict__ KWG, const unsigned* __restrict__ KWH,
    u16* __restrict__ ELH)
{
  __shared__ __align__(16) unsigned su[6272];
  __shared__ __align__(16) unsigned ku[1568];    // [jk49][cl4][tap8] (w,w) f16 pairs

  int bid = blockIdx.x;                    // 3136 = 2 * 32 * 49
  int b = bid / 1568; int rr = bid - b*1568;
  int cg = rr / 49; int s = rr % 49;
  int th = s / 7, tw = s % 7;
  int tid = threadIdx.x;
  int h0g = th*8, w0g = tw*8;
  size_t tb = (size_t)(b*32 + cg)*200704;  // u16 slab base (GP/HP/ELH identical value)

  int cl = tid & 3, w0 = (tid>>2)&7, h0 = tid>>5;
  int wv = tid >> 6, lane = tid & 63;

  // ---- precompute per-thread staging chunk offsets (reused: 2 halves x 2 passes) ----
  unsigned soff[4]; bool sval[4];
#pragma unroll
  for (int ss = 0; ss < 4; ++ss){
    int idx = wv*64 + ss*256 + lane;
    sval[ss] = (idx < 784);
    int pos = idx >> 2, pcl = idx & 3;
    int hh = pos / 14, ww = pos - hh*14;
    int hg = h0g + hh - 3; if (hg < 0) hg += 56; else if (hg >= 56) hg -= 56;
    int wg = w0g + ww - 3; if (wg < 0) wg += 56; else if (wg >= 56) wg -= 56;
    soff[ss] = (unsigned)(((hg*56 + wg)*4 + pcl)*32);   // byte offset within slab
  }
  const char* gpb = (const char*)(GP + tb);
  const char* hpb = (const char*)(HP + tb);

  auto wload = [&](const unsigned* KW){
    for (int p = tid; p < 1568; p += 256){
      int tap = p & 7, c2 = (p>>3)&3, jk = p>>5;
      ku[p] = KW[(jk*128 + cg*4 + c2)*8 + tap];
    }
  };
  auto stagepass = [&](const char* Pb){
#pragma unroll
    for (int half = 0; half < 2; ++half){
#pragma unroll
      for (int ss = 0; ss < 4; ++ss){
        if (sval[ss])
          gld_lds16(Pb + soff[ss] + half*16,
                    (char*)su + half*12544 + (wv*64 + ss*256)*16);
      }
    }
  };
  auto convpass = [&](__half2* A){
#pragma unroll
    for (int p = 0; p < 8; ++p) A[p] = u2h(0u);
    for (int j = 0; j < 7; ++j){
      int hh = h0 + 6 - j;
      int cb0 = ((hh*14 + w0)*4 + cl)*4;     // u32 index at k=6
      int wb0 = (j*28 + cl)*8;               // u32 index at k=0
#pragma unroll
      for (int k = 0; k < 7; ++k){
        const unsigned* sp = &su[cb0 + (6-k)*16];
        uint4 da = *(const uint4*)sp;
        uint4 db = *(const uint4*)(sp + 3136);
        unsigned P[8] = {da.x,da.y,da.z,da.w,db.x,db.y,db.z,db.w};
        unsigned M[8];
#pragma unroll
        for (int p = 0; p < 8; ++p) M[p] = (P[p]>>16) | (P[(p+1)&7]<<16);
        const unsigned* kp = &ku[wb0 + k*32];
        uint4 w4 = *(const uint4*)kp;
        unsigned w5 = kp[4];
        // out[t] += sum_i w[i] * X[(t-i+2)&15]
#pragma unroll
        for (int p = 0; p < 8; ++p){
          A[p] = __hfma2(u2h(w4.x), u2h(P[(p+1)&7]), A[p]);   // i=0: X[t+2]
          A[p] = __hfma2(u2h(w4.y), u2h(M[p]),       A[p]);   // i=1: X[t+1]
          A[p] = __hfma2(u2h(w4.z), u2h(P[p]),       A[p]);   // i=2: X[t]
          A[p] = __hfma2(u2h(w4.w), u2h(M[(p+7)&7]), A[p]);   // i=3: X[t-1]
          A[p] = __hfma2(u2h(w5),   u2h(P[(p+7)&7]), A[p]);   // i=4: X[t-2]
        }
      }
    }
  };

  __half2 Ag[8], Ah[8];
  wload(KWG);
  stagepass(gpb);
  __syncthreads();          // drains vmcnt: global_load_lds data resident
  convpass(Ag);
  __syncthreads();          // conv reads done before restage overwrites
  wload(KWH);
  stagepass(hpb);
  __syncthreads();
  convpass(Ah);

  float xg[16], xh[16];
#pragma unroll
  for (int p = 0; p < 8; ++p){
    float2 g2 = __half22float2(Ag[p]); xg[2*p] = g2.x; xg[2*p+1] = g2.y;
    float2 h2 = __half22float2(Ah[p]); xh[2*p] = h2.x; xh[2*p+1] = h2.y;
  }

  // pointwise + scan over T + store exp(log_h) (bf16)
  size_t ob = tb + ((size_t)(h0g + h0)*56 + (w0g + w0))*4 + cl;
  float lh = 0.f;
#pragma unroll
  for (int t = 0; t < 16; ++t){
    float g  = xg[t];
    float spg = fmaxf(g, 0.f) + __logf(1.f + __expf(-fabsf(g)));  // softplus(g)
    float lf  = -spg;                                             // log(1-z)
    float hv  = xh[t];
    float lv  = (g - spg) + __logf(hv*hv + 1e-6f);                // log z + log h~^2
    if (t == 0) lh = lv;
    else {
      float a_ = lf + lh;
      float mx = fmaxf(a_, lv);
      lh = mx + __logf(1.f + __expf(-fabsf(a_ - lv)));
    }
    ELH[ob + (size_t)t*12544] = f2b(__expf(lh));
  }
}

// ---------------- K34 v3: M=128 (row-tiles t2 and t2+8), gld_lds double-buffered W staging ----------------
// Phase A: GEMM+LN for both tiles -> sX (dies before staging; aliases sW).
// Phase B: per nt: issue stage(nt+1) into other buffer -> compute both tiles -> vmcnt(0)+s_barrier.
// No data in VGPRs for staging (global_load_lds) => nothing to spill (R2 post-mortem).
__global__ __launch_bounds__(256, 2) void k34_gemm_ln_mlp(
    const u16* __restrict__ ELH, const u16* __restrict__ WoT,
    const u16* __restrict__ W1T, const u16* __restrict__ W2T,
    const u16* __restrict__ PRM,
    const void* __restrict__ xraw, void* __restrict__ outv)
{
  __shared__ __align__(16) u16 smem[37376];   // 74,752 B -> 2 blocks/CU
  u16* sW0 = smem;               // 16384 u16 (32 KB)
  u16* sW1 = smem + 16384;       // 16384 u16
  u16* sXp = smem;               // 2*64*136 = 17408 u16 (phase A only; dead before staging)
  u16* sH  = smem + 32768;       // 4 waves * 1152 u16

  int bid = blockIdx.x;          // 784 = 2b * 8t2 * 49s
  int b = bid / 392; int rem = bid - b*392;
  int t2 = rem / 49; int s2 = rem - t2*49;
  int hw0 = s2 * 64;
  int tid = threadIdx.x;
  int wv = tid >> 6, lane = tid & 63;
  int lrow = lane & 15, q = lane >> 4;
  const bool f32io = input_is_f32(xraw);

  // ---- phase A: ssm_out = elh@Wo + bo, LayerNorm -> sX (tiles A: t2, B: t2+8) ----
  {
    int hw = hw0 + wv*16 + lrow;
    size_t tbA = ((size_t)(b*512) + t2)*3136;      // ((b*32+0)*16 + t2)*3136
    size_t tbB = tbA + (size_t)8*3136;
    union Cvt { uint4 u; bf16x8 v; };
    bf16x8 eA[4], eB[4];
#pragma unroll
    for (int kt = 0; kt < 4; ++kt){
      int cg0 = kt*8 + q*2;
      size_t eoA = (tbA + (size_t)cg0*50176 + hw)*4;
      size_t eoB = (tbB + (size_t)cg0*50176 + hw)*4;
      uint2 lo = *(const uint2*)(ELH + eoA);
      uint2 hi = *(const uint2*)(ELH + eoA + (size_t)50176*4);
      Cvt c1; c1.u = make_uint4(lo.x, lo.y, hi.x, hi.y); eA[kt] = c1.v;
      uint2 lo2 = *(const uint2*)(ELH + eoB);
      uint2 hi2 = *(const uint2*)(ELH + eoB + (size_t)50176*4);
      Cvt c2; c2.u = make_uint4(lo2.x, lo2.y, hi2.x, hi2.y); eB[kt] = c2.v;
    }

    float vA[8][4], vB[8][4];
#pragma unroll
    for (int nt = 0; nt < 8; ++nt){
      f32x4 aacc = {0.f,0.f,0.f,0.f}, bacc = {0.f,0.f,0.f,0.f};
      const u16* wr = WoT + (nt*16 + lrow)*128 + q*8;
#pragma unroll
      for (int kt = 0; kt < 4; ++kt){
        bf16x8 bfr = *(const bf16x8*)(wr + kt*32);
        aacc = MFMA16(eA[kt], bfr, aacc);
        bacc = MFMA16(eB[kt], bfr, bacc);
      }
      float bv = b2f(PRM[256 + nt*16 + lrow]);
#pragma unroll
      for (int i = 0; i < 4; ++i){ vA[nt][i] = aacc[i] + bv; vB[nt][i] = bacc[i] + bv; }
    }

#pragma unroll
    for (int i = 0; i < 4; ++i){
      float smA=0.f, sqA=0.f, smB=0.f, sqB=0.f;
#pragma unroll
      for (int nt = 0; nt < 8; ++nt){
        float a_ = vA[nt][i]; smA += a_; sqA = fmaf(a_, a_, sqA);
        float b_ = vB[nt][i]; smB += b_; sqB = fmaf(b_, b_, sqB);
      }
#pragma unroll
      for (int m = 1; m < 16; m <<= 1){
        smA += __shfl_xor(smA, m, 64); sqA += __shfl_xor(sqA, m, 64);
        smB += __shfl_xor(smB, m, 64); sqB += __shfl_xor(sqB, m, 64);
      }
      float mA = smA*(1.f/128.f), rA = rsqrtf(sqA*(1.f/128.f) - mA*mA + 1e-6f);
      float mB = smB*(1.f/128.f), rB = rsqrtf(sqB*(1.f/128.f) - mB*mB + 1e-6f);
      int r = wv*16 + q*4 + i;
#pragma unroll
      for (int nt = 0; nt < 8; ++nt){
        int c = nt*16 + lrow;
        float ls = b2f(PRM[384 + c]), lb = b2f(PRM[512 + c]);
        sXp[r*136 + c]        = f2b((vA[nt][i] - mA)*rA*ls + lb);
        sXp[8704 + r*136 + c] = f2b((vB[nt][i] - mB)*rB*ls + lb);
      }
    }
  }

  // a-frags: rows written by this same wave -> readable without barrier
  bf16x8 aA[4], aB[4];
#pragma unroll
  for (int kt = 0; kt < 4; ++kt){
    aA[kt] = *(const bf16x8*)&sXp[(wv*16 + lrow)*136 + kt*32 + q*8];
    aB[kt] = *(const bf16x8*)&sXp[8704 + (wv*16 + lrow)*136 + kt*32 + q*8];
  }
  __syncthreads();   // all waves done with sX before W staging overwrites it

  // per-thread W-tile global srcs (nt advance: W1 part +8192, W2 part +64)
  const u16* wsrc[8];
#pragma unroll
  for (int r = 0; r < 8; ++r){
    int c = r*4 + wv;
    if (c < 16){
      int j = c >> 2, kt = c & 3;
      wsrc[r] = W1T + (size_t)(j*16 + lrow)*128 + kt*32 + q*8;
    } else {
      int c2 = c - 16; int jo = c2 >> 1, kt2 = c2 & 1;
      wsrc[r] = W2T + (size_t)(jo*16 + lrow)*512 + kt2*32 + q*8;
    }
  }
  auto stage = [&](u16* buf, int nt){
#pragma unroll
    for (int r = 0; r < 8; ++r){
      int c = r*4 + wv;
      const u16* src = wsrc[r] + (c < 16 ? (size_t)nt*8192 : (size_t)nt*64);
      gld_lds16(src, buf + c*512);            // dest wave-uniform; HW adds lane*16B
    }
  };

  f32x4 accA[8], accB[8];
#pragma unroll
  for (int jo = 0; jo < 8; ++jo){ accA[jo] = (f32x4){0.f,0.f,0.f,0.f}; accB[jo] = (f32x4){0.f,0.f,0.f,0.f}; }
  u16* sHw = sH + wv*1152;

  stage(sW0, 0);
  asm volatile("s_waitcnt vmcnt(0)" ::: "memory");
  __builtin_amdgcn_s_barrier();

  auto mlpstep = [&](int nt, u16* wcur, u16* wnxt, bool do_stage){
    if (do_stage) stage(wnxt, nt+1);          // in flight under both tiles' compute
    // ---- tile A ----
#pragma unroll
    for (int js = 0; js < 4; ++js){
      f32x4 hc = {0.f,0.f,0.f,0.f};
#pragma unroll
      for (int kt = 0; kt < 4; ++kt)
        hc = MFMA16(aA[kt], *(const bf16x8*)&wcur[(js*4 + kt)*512 + lane*8], hc);
      float bv = b2f(PRM[640 + nt*64 + js*16 + lrow]);
#pragma unroll
      for (int i = 0; i < 4; ++i){
        float v = hc[i] + bv;
        float u = 0.79788456080286535588f*(v + 0.044715f*v*v*v);
        float su_ = __expf(-2.f*u);
        float gl = v * __builtin_amdgcn_rcpf(1.f + su_);
        sHw[(q*4 + i)*72 + js*16 + lrow] = (u16)(__float_as_uint(gl) >> 16);
      }
    }
#pragma unroll
    for (int kt2 = 0; kt2 < 2; ++kt2){
      bf16x8 af = *(const bf16x8*)&sHw[lrow*72 + kt2*32 + q*8];
#pragma unroll
      for (int jo = 0; jo < 8; ++jo)
        accA[jo] = MFMA16(af, *(const bf16x8*)&wcur[(16 + jo*2 + kt2)*512 + lane*8], accA[jo]);
    }
    // ---- tile B (sHw reuse: same-wave DS ordering) ----
#pragma unroll
    for (int js = 0; js < 4; ++js){
      f32x4 hc = {0.f,0.f,0.f,0.f};
#pragma unroll
      for (int kt = 0; kt < 4; ++kt)
        hc = MFMA16(aB[kt], *(const bf16x8*)&wcur[(js*4 + kt)*512 + lane*8], hc);
      float bv = b2f(PRM[640 + nt*64 + js*16 + lrow]);
#pragma unroll
      for (int i = 0; i < 4; ++i){
        float v = hc[i] + bv;
        float u = 0.79788456080286535588f*(v + 0.044715f*v*v*v);
        float su_ = __expf(-2.f*u);
        float gl = v * __builtin_amdgcn_rcpf(1.f + su_);
        sHw[(q*4 + i)*72 + js*16 + lrow] = (u16)(__float_as_uint(gl) >> 16);
      }
    }
#pragma unroll
    for (int kt2 = 0; kt2 < 2; ++kt2){
      bf16x8 af = *(const bf16x8*)&sHw[lrow*72 + kt2*32 + q*8];
#pragma unroll
      for (int jo = 0; jo < 8; ++jo)
        accB[jo] = MFMA16(af, *(const bf16x8*)&wcur[(16 + jo*2 + kt2)*512 + lane*8], accB[jo]);
    }
    asm volatile("s_waitcnt vmcnt(0)" ::: "memory");   // staged tile landed; readers done next
    __builtin_amdgcn_s_barrier();
  };

  for (int nt2 = 0; nt2 < 4; ++nt2){
    mlpstep(2*nt2,     sW0, sW1, true);
    mlpstep(2*nt2 + 1, sW1, sW0, nt2 < 3);
  }

  // ---- epilogue: out = (acc + b2)*gamma + x  (both tiles) ----
  size_t rowA0 = ((size_t)(b*16 + t2))*3136 + hw0 + wv*16 + q*4;
  size_t rowB0 = rowA0 + (size_t)8*3136;
#pragma unroll
  for (int jo = 0; jo < 8; ++jo){
    int c = jo*16 + lrow;
    float bv  = b2f(PRM[1152 + c]);
    float gmv = b2f(PRM[1280 + c]);
#pragma unroll
    for (int i = 0; i < 4; ++i){
      size_t rA = rowA0 + i, rB = rowB0 + i;
      float yA = accA[jo][i] + bv, yB = accB[jo][i] + bv;
      if (f32io){
        float resA = ((const float*)xraw)[rA*128 + c];
        float resB = ((const float*)xraw)[rB*128 + c];
        ((float*)outv)[rA*128 + c] = yA*gmv + resA;
        ((float*)outv)[rB*128 + c] = yB*gmv + resB;
      } else {
        float resA = b2f(((const u16*)xraw)[rA*128 + c]);
        float resB = b2f(((const u16*)xraw)[rB*128 + c]);
        ((u16*)outv)[rA*128 + c] = f2b(yA*gmv + resA);
        ((u16*)outv)[rB*128 + c] = f2b(yB*gmv + resB);
      }
    }
  }
}

// ---------------- launch ----------------
extern "C" void kernel_launch(void* const* d_in, const int* in_sizes, int n_in,
                              void* d_out, int out_size, void* d_ws, size_t ws_size,
                              hipStream_t stream)
{
  const void* x   = d_in[0];
  const void* Wg  = d_in[1];
  const void* bg  = d_in[2];
  const void* Wh  = d_in[3];
  const void* bh  = d_in[4];
  const void* gk  = d_in[5];
  const void* hk  = d_in[6];
  const void* Wo  = d_in[7];
  const void* bo  = d_in[8];
  const void* lns = d_in[9];
  const void* lnb = d_in[10];
  const void* W1  = d_in[11];
  const void* b1  = d_in[12];
  const void* W2  = d_in[13];
  const void* b2  = d_in[14];
  const void* gm  = d_in[15];

  char* ws = (char*)d_ws;
  u16* GP  = (u16*)(ws + 0);              // 25,690,112 B each (f16)
  u16* HP  = (u16*)(ws + 25690112);
  u16* ELH = (u16*)(ws + 51380224);       // bf16
  u16* XB  = (u16*)(ws + 77070336);       // canonical bf16 x
  u16* WgT = (u16*)(ws + 102760448);
  u16* WhT = WgT + 16384;
  u16* WoT = WhT + 16384;
  u16* W1T = WoT + 16384;
  u16* W2T = W1T + 65536;
  unsigned* KWG = (unsigned*)(W2T + 65536);    // 50,176 u32 each
  unsigned* KWH = KWG + 50176;
  u16* PRM = (u16*)(KWH + 50176);

  k0_prep        <<<dim3(512),  dim3(256), 0, stream>>>(x, Wg, Wh, Wo, W1, W2, gk, hk,
                                                        bg, bh, bo, lns, lnb, b1, b2, gm,
                                                        XB, WgT, WhT, WoT, W1T, W2T, KWG, KWH, PRM);
  k1_dualgemm    <<<dim3(1568), dim3(256), 0, stream>>>(XB, WgT, WhT, PRM, GP, HP);
  k2_conv_scan   <<<dim3(3136), dim3(256), 0, stream>>>(GP, HP, KWG, KWH, ELH);
  k34_gemm_ln_mlp<<<dim3(784),  dim3(256), 0, stream>>>(ELH, WoT, W1T, W2T, PRM, x, (void*)d_out);
}

// Round 4
// 445.999 us; speedup vs baseline: 1.2834x; 1.0171x over previous
//
#include <hip/hip_runtime.h>
#include <hip/hip_bf16.h>
#include <hip/hip_fp16.h>
#include <cstdint>
#include <cstddef>

typedef unsigned short u16;
typedef __attribute__((ext_vector_type(8))) short bf16x8;
typedef __attribute__((ext_vector_type(4))) float f32x4;

#define MFMA16(a,b,c) __builtin_amdgcn_mfma_f32_16x16x32_bf16((a),(b),(c),0,0,0)

// B=2 T=16 H=W=56 C=128  HW=3136  N=100352  HID=512
// GP/HP (f16) layout: [b][cg32][hw3136][cl4][t16]  (t contiguous, 32B per (hw,cl))
//   u16 idx = (((b*32+cg)*3136 + hw)*4 + cl)*16 + t          slab = 200704 u16/(b,cg)
// ELH (bf16) layout: (((b*32+cg)*16 + t)*3136 + hw)*4 + cl
// KWG/KWH (u32 (w,w) f16 dup): [c128][j7][k7][tap5]  idx = c*245 + j*35 + k*5 + tap

static __device__ __forceinline__ float b2f(u16 u){ return __uint_as_float(((unsigned)u)<<16); }
static __device__ __forceinline__ u16 f2b(float f){
  unsigned u = __float_as_uint(f);
  return (u16)((u + 0x7fffu + ((u>>16)&1u)) >> 16);
}
static __device__ __forceinline__ u16 f2h(float f){ return __half_as_ushort(__float2half(f)); }
static __device__ __forceinline__ __half2 u2h(unsigned u){ union{unsigned u;__half2 h;}c; c.u=u; return c.h; }

// async global->LDS 16B: LDS dest = wave-uniform base + lane*16, global src per-lane
static __device__ __forceinline__ void gld_lds16(const void* g, void* l){
  __builtin_amdgcn_global_load_lds(
      (const __attribute__((address_space(1))) void*)g,
      (__attribute__((address_space(3))) void*)l, 16, 0, 0);
}

// dtype detector: sample 64 even-index u16 words of x. bf16 N(0,1) data -> exponent
// field in [100,140] essentially always; f32 -> mantissa halves, ~uniform exponent.
static __device__ __forceinline__ bool input_is_f32(const void* xp){
  const u16* u = (const u16*)xp;
  int cnt = 0;
#pragma unroll
  for (int i = 0; i < 64; ++i){
    unsigned e = (u[2*i] >> 7) & 0xFF;
    cnt += (e >= 100 && e <= 140) ? 1 : 0;
  }
  return cnt < 32;
}

static __device__ __forceinline__ u16 ldb(const void* p, int i, bool f32){
  return f32 ? f2b(((const float*)p)[i]) : ((const u16*)p)[i];
}
static __device__ __forceinline__ float ldf(const void* p, int i, bool f32){
  return f32 ? ((const float*)p)[i] : b2f(((const u16*)p)[i]);
}

// ---------------- K0: canonicalize inputs (+ transposes + conv weight relayout) ----------------
__global__ __launch_bounds__(256) void k0_prep(
    const void* __restrict__ x,
    const void* __restrict__ Wg, const void* __restrict__ Wh, const void* __restrict__ Wo,
    const void* __restrict__ W1, const void* __restrict__ W2,
    const void* __restrict__ gk, const void* __restrict__ hk,
    const void* __restrict__ bg, const void* __restrict__ bh, const void* __restrict__ bo,
    const void* __restrict__ lns, const void* __restrict__ lnb,
    const void* __restrict__ b1, const void* __restrict__ b2, const void* __restrict__ gm,
    u16* __restrict__ XB,
    u16* __restrict__ WgT, u16* __restrict__ WhT, u16* __restrict__ WoT,
    u16* __restrict__ W1T, u16* __restrict__ W2T,
    unsigned* __restrict__ KWG, unsigned* __restrict__ KWH, u16* __restrict__ PRM)
{
  const bool f32 = input_is_f32(x);
  int tid = blockIdx.x*blockDim.x + threadIdx.x;
  int np  = gridDim.x*blockDim.x;

  // x -> XB (bf16), 2 elements per u32 store
  if (f32){
    const float* xf = (const float*)x;
    for (int p = tid; p < 6422528; p += np){
      unsigned v = (unsigned)f2b(xf[2*p]) | ((unsigned)f2b(xf[2*p+1]) << 16);
      ((unsigned*)XB)[p] = v;
    }
  } else {
    const unsigned* xu = (const unsigned*)x;
    for (int p = tid; p < 6422528; p += np) ((unsigned*)XB)[p] = xu[p];
  }

  for (int p = tid; p < 16384; p += np){           // 128x128 transposes
    int n = p>>7, k = p&127;
    WgT[p] = ldb(Wg, k*128+n, f32);
    WhT[p] = ldb(Wh, k*128+n, f32);
    WoT[p] = ldb(Wo, k*128+n, f32);
  }
  for (int p = tid; p < 65536; p += np){           // W1 (128,512) -> W1T (512,128)
    int n = p>>7, k = p&127;
    W1T[p] = ldb(W1, k*512+n, f32);
  }
  for (int p = tid; p < 65536; p += np){           // W2 (512,128) -> W2T (128,512)
    int n = p>>9, k = p&511;
    W2T[p] = ldb(W2, k*128+n, f32);
  }
  // conv kernels: [c128][j7][k7][tap5] u32 = f16 weight duplicated (w,w)
  for (int p = tid; p < 31360; p += np){
    int c = p / 245; int r = p - c*245;
    int j = r / 35;  int r2 = r - j*35;
    int k = r2 / 5;  int tap = r2 - k*5;
    int s = (c*5+tap)*49 + (j*7+k);
    unsigned g16 = f2h(ldf(gk, s, f32)), h16 = f2h(ldf(hk, s, f32));
    KWG[p] = g16 | (g16<<16);
    KWH[p] = h16 | (h16<<16);
  }
  // param block (bf16): bg@0 bh@128 bo@256 lns@384 lnb@512 b1@640 b2@1152 gamma@1280
  for (int p = tid; p < 1408; p += np){
    const void* src; int off;
    if      (p < 128)  { src = bg;  off = p; }
    else if (p < 256)  { src = bh;  off = p-128; }
    else if (p < 384)  { src = bo;  off = p-256; }
    else if (p < 512)  { src = lns; off = p-384; }
    else if (p < 640)  { src = lnb; off = p-512; }
    else if (p < 1152) { src = b1;  off = p-640; }
    else if (p < 1280) { src = b2;  off = p-1152; }
    else               { src = gm;  off = p-1280; }
    PRM[p] = ldb(src, off, f32);
  }
}

// ---------------- K1: dual GEMM  gate = x@Wg+bg, hidden = x@Wh+bh (f16 out, t-contiguous) ----------------
__global__ __launch_bounds__(256) void k1_dualgemm(
    const u16* __restrict__ XB, const u16* __restrict__ WgT, const u16* __restrict__ WhT,
    const u16* __restrict__ PRM,
    u16* __restrict__ GP, u16* __restrict__ HP)
{
  int bid = blockIdx.x;                  // 1568 = 2b * 784 hw-groups
  int b = bid / 784; int hw = (bid % 784)*4 + (threadIdx.x >> 6);
  int lane = threadIdx.x & 63;
  int lrow = lane & 15, q = lane >> 4;

  bf16x8 a[4];   // A row (in-tile) = lrow = t; k-cols q*8 + kt*32
  const u16* xr = XB + ((size_t)(b*16 + lrow)*3136 + hw)*128 + q*8;
#pragma unroll
  for (int kt = 0; kt < 4; ++kt) a[kt] = *(const bf16x8*)(xr + kt*32);

#pragma unroll
  for (int mat = 0; mat < 2; ++mat){
    const u16* WT  = mat ? WhT : WgT;
    const u16* bia = PRM + (mat ? 128 : 0);
    u16* out       = mat ? HP  : GP;
#pragma unroll
    for (int nt = 0; nt < 8; ++nt){
      f32x4 acc = {0.f,0.f,0.f,0.f};
      const u16* wr = WT + (nt*16 + lrow)*128 + q*8;
#pragma unroll
      for (int kt = 0; kt < 4; ++kt){
        bf16x8 bfr = *(const bf16x8*)(wr + kt*32);
        acc = MFMA16(a[kt], bfr, acc);
      }
      int c = nt*16 + lrow;              // C col = output channel
      float bv = b2f(bia[c]);
      size_t base = (((size_t)(b*32 + (c>>2))*3136 + hw)*4 + (c&3))*16 + q*4;
      ushort4 pk;
      pk.x = f2h(acc[0] + bv); pk.y = f2h(acc[1] + bv);
      pk.z = f2h(acc[2] + bv); pk.w = f2h(acc[3] + bv);
      *(ushort4*)(out + base) = pk;      // t = q*4 .. q*4+3
    }
  }
}

// ---------------- K2: circular 5x7x7 depthwise conv (packed f16) + scan ----------------
// Wave = one channel (cl = wave id), 64 lanes = 8x8 spatial positions.
// Weights: wave-uniform pointer (readfirstlane) -> scalar loads, no LDS for weights.
// su chunk permutation (source-side, LDS linear): chunk 4*pos+d holds channel d ^ (hh&3)
// so the wave-per-channel b128 reads stay bank-uniform (8 lanes per 16B frame-slot).
__global__ __launch_bounds__(256, 6) void k2_conv_scan(
    const u16* __restrict__ GP, const u16* __restrict__ HP,
    const unsigned* __restrict__ KWG, const unsigned* __restrict__ KWH,
    u16* __restrict__ ELH)
{
  __shared__ __align__(16) unsigned su[6272];   // 25,088 B

  int bid = blockIdx.x;                    // 3136 = 2 * 32 * 49
  int b = bid / 1568; int rr = bid - b*1568;
  int cg = rr / 49; int s = rr % 49;
  int th = s / 7, tw = s % 7;
  int tid = threadIdx.x;
  int h0g = th*8, w0g = tw*8;
  size_t tb = (size_t)(b*32 + cg)*200704;  // u16 slab base (GP/HP/ELH identical value)

  int wv = tid >> 6, lane = tid & 63;
  int cl = wv;                             // wave-uniform channel-in-group
  int w0 = lane & 7, h0 = lane >> 3;

  int cu = __builtin_amdgcn_readfirstlane(cg*4 + wv);
  const unsigned* kwg = KWG + (size_t)cu*245;
  const unsigned* kwh = KWH + (size_t)cu*245;

  // ---- staging chunk offsets (chunk idx = 4*pos + d; fetch channel d ^ (hh&3)) ----
  unsigned soff[4]; bool sval[4];
#pragma unroll
  for (int ss = 0; ss < 4; ++ss){
    int idx = wv*64 + ss*256 + lane;
    sval[ss] = (idx < 784);
    int pos = idx >> 2, d = idx & 3;
    int hh = pos / 14, ww = pos - hh*14;
    int pcl = d ^ (hh & 3);
    int hg = h0g + hh - 3; if (hg < 0) hg += 56; else if (hg >= 56) hg -= 56;
    int wg = w0g + ww - 3; if (wg < 0) wg += 56; else if (wg >= 56) wg -= 56;
    soff[ss] = (unsigned)(((hg*56 + wg)*4 + pcl)*32);   // byte offset within slab
  }
  const char* gpb = (const char*)(GP + tb);
  const char* hpb = (const char*)(HP + tb);

  auto stagepass = [&](const char* Pb){
#pragma unroll
    for (int half = 0; half < 2; ++half){
#pragma unroll
      for (int ss = 0; ss < 4; ++ss){
        if (sval[ss])
          gld_lds16(Pb + soff[ss] + half*16,
                    (char*)su + half*12544 + (wv*64 + ss*256)*16);
      }
    }
  };
  auto convpass = [&](__half2* A, const unsigned* kw){
#pragma unroll
    for (int p = 0; p < 8; ++p) A[p] = u2h(0u);
    for (int j = 0; j < 7; ++j){
      int hh = h0 + 6 - j;
      // chunk for (pos, cl): 4*pos + (cl ^ (hh&3));  u32 base = pos*16 + (cl^(hh&3))*4
      int cb0 = (hh*14 + w0)*16 + ((cl ^ (hh & 3)) << 2);   // at k=6 (pos offset +0)
      // weights for this j: 35 u32, wave-uniform -> scalar loads
      unsigned wj[35];
#pragma unroll
      for (int i = 0; i < 35; ++i) wj[i] = kw[j*35 + i];
#pragma unroll
      for (int k = 0; k < 7; ++k){
        const unsigned* sp = &su[cb0 + (6-k)*16];
        uint4 da = *(const uint4*)sp;
        uint4 db = *(const uint4*)(sp + 3136);
        unsigned P[8] = {da.x,da.y,da.z,da.w,db.x,db.y,db.z,db.w};
        unsigned M[8];
#pragma unroll
        for (int p = 0; p < 8; ++p) M[p] = (P[p]>>16) | (P[(p+1)&7]<<16);
        // out[t] += sum_i w[i] * X[(t-i+2)&15]
#pragma unroll
        for (int p = 0; p < 8; ++p){
          A[p] = __hfma2(u2h(wj[k*5+0]), u2h(P[(p+1)&7]), A[p]);   // i=0: X[t+2]
          A[p] = __hfma2(u2h(wj[k*5+1]), u2h(M[p]),       A[p]);   // i=1: X[t+1]
          A[p] = __hfma2(u2h(wj[k*5+2]), u2h(P[p]),       A[p]);   // i=2: X[t]
          A[p] = __hfma2(u2h(wj[k*5+3]), u2h(M[(p+7)&7]), A[p]);   // i=3: X[t-1]
          A[p] = __hfma2(u2h(wj[k*5+4]), u2h(P[(p+7)&7]), A[p]);   // i=4: X[t-2]
        }
      }
    }
  };

  __half2 Ag[8], Ah[8];
  stagepass(gpb);
  __syncthreads();          // drains vmcnt: global_load_lds data resident
  convpass(Ag, kwg);
  __syncthreads();          // conv reads done before restage overwrites
  stagepass(hpb);
  __syncthreads();
  convpass(Ah, kwh);

  float xg[16], xh[16];
#pragma unroll
  for (int p = 0; p < 8; ++p){
    float2 g2 = __half22float2(Ag[p]); xg[2*p] = g2.x; xg[2*p+1] = g2.y;
    float2 h2 = __half22float2(Ah[p]); xh[2*p] = h2.x; xh[2*p+1] = h2.y;
  }

  // pointwise + scan over T + store exp(log_h) (bf16)
  size_t ob = tb + ((size_t)(h0g + h0)*56 + (w0g + w0))*4 + cl;
  float lh = 0.f;
#pragma unroll
  for (int t = 0; t < 16; ++t){
    float g  = xg[t];
    float spg = fmaxf(g, 0.f) + __logf(1.f + __expf(-fabsf(g)));  // softplus(g)
    float lf  = -spg;                                             // log(1-z)
    float hv  = xh[t];
    float lv  = (g - spg) + __logf(hv*hv + 1e-6f);                // log z + log h~^2
    if (t == 0) lh = lv;
    else {
      float a_ = lf + lh;
      float mx = fmaxf(a_, lv);
      lh = mx + __logf(1.f + __expf(-fabsf(a_ - lv)));
    }
    ELH[ob + (size_t)t*12544] = f2b(__expf(lh));
  }
}

// ---------------- K34: M=128 (row-tiles t2 and t2+8), gld_lds double-buffered W staging ----------------
__global__ __launch_bounds__(256, 2) void k34_gemm_ln_mlp(
    const u16* __restrict__ ELH, const u16* __restrict__ WoT,
    const u16* __restrict__ W1T, const u16* __restrict__ W2T,
    const u16* __restrict__ PRM,
    const void* __restrict__ xraw, void* __restrict__ outv)
{
  __shared__ __align__(16) u16 smem[37376];   // 74,752 B -> 2 blocks/CU
  u16* sW0 = smem;               // 16384 u16 (32 KB)
  u16* sW1 = smem + 16384;       // 16384 u16
  u16* sXp = smem;               // 2*64*136 = 17408 u16 (phase A only; dead before staging)
  u16* sH  = smem + 32768;       // 4 waves * 1152 u16

  int bid = blockIdx.x;          // 784 = 2b * 8t2 * 49s
  int b = bid / 392; int rem = bid - b*392;
  int t2 = rem / 49; int s2 = rem - t2*49;
  int hw0 = s2 * 64;
  int tid = threadIdx.x;
  int wv = tid >> 6, lane = tid & 63;
  int lrow = lane & 15, q = lane >> 4;
  const bool f32io = input_is_f32(xraw);

  // ---- phase A: ssm_out = elh@Wo + bo, LayerNorm -> sX (tiles A: t2, B: t2+8) ----
  {
    int hw = hw0 + wv*16 + lrow;
    size_t tbA = ((size_t)(b*512) + t2)*3136;      // ((b*32+0)*16 + t2)*3136
    size_t tbB = tbA + (size_t)8*3136;
    union Cvt { uint4 u; bf16x8 v; };
    bf16x8 eA[4], eB[4];
#pragma unroll
    for (int kt = 0; kt < 4; ++kt){
      int cg0 = kt*8 + q*2;
      size_t eoA = (tbA + (size_t)cg0*50176 + hw)*4;
      size_t eoB = (tbB + (size_t)cg0*50176 + hw)*4;
      uint2 lo = *(const uint2*)(ELH + eoA);
      uint2 hi = *(const uint2*)(ELH + eoA + (size_t)50176*4);
      Cvt c1; c1.u = make_uint4(lo.x, lo.y, hi.x, hi.y); eA[kt] = c1.v;
      uint2 lo2 = *(const uint2*)(ELH + eoB);
      uint2 hi2 = *(const uint2*)(ELH + eoB + (size_t)50176*4);
      Cvt c2; c2.u = make_uint4(lo2.x, lo2.y, hi2.x, hi2.y); eB[kt] = c2.v;
    }

    float vA[8][4], vB[8][4];
#pragma unroll
    for (int nt = 0; nt < 8; ++nt){
      f32x4 aacc = {0.f,0.f,0.f,0.f}, bacc = {0.f,0.f,0.f,0.f};
      const u16* wr = WoT + (nt*16 + lrow)*128 + q*8;
#pragma unroll
      for (int kt = 0; kt < 4; ++kt){
        bf16x8 bfr = *(const bf16x8*)(wr + kt*32);
        aacc = MFMA16(eA[kt], bfr, aacc);
        bacc = MFMA16(eB[kt], bfr, bacc);
      }
      float bv = b2f(PRM[256 + nt*16 + lrow]);
#pragma unroll
      for (int i = 0; i < 4; ++i){ vA[nt][i] = aacc[i] + bv; vB[nt][i] = bacc[i] + bv; }
    }

#pragma unroll
    for (int i = 0; i < 4; ++i){
      float smA=0.f, sqA=0.f, smB=0.f, sqB=0.f;
#pragma unroll
      for (int nt = 0; nt < 8; ++nt){
        float a_ = vA[nt][i]; smA += a_; sqA = fmaf(a_, a_, sqA);
        float b_ = vB[nt][i]; smB += b_; sqB = fmaf(b_, b_, sqB);
      }
#pragma unroll
      for (int m = 1; m < 16; m <<= 1){
        smA += __shfl_xor(smA, m, 64); sqA += __shfl_xor(sqA, m, 64);
        smB += __shfl_xor(smB, m, 64); sqB += __shfl_xor(sqB, m, 64);
      }
      float mA = smA*(1.f/128.f), rA = rsqrtf(sqA*(1.f/128.f) - mA*mA + 1e-6f);
      float mB = smB*(1.f/128.f), rB = rsqrtf(sqB*(1.f/128.f) - mB*mB + 1e-6f);
      int r = wv*16 + q*4 + i;
#pragma unroll
      for (int nt = 0; nt < 8; ++nt){
        int c = nt*16 + lrow;
        float ls = b2f(PRM[384 + c]), lb = b2f(PRM[512 + c]);
        sXp[r*136 + c]        = f2b((vA[nt][i] - mA)*rA*ls + lb);
        sXp[8704 + r*136 + c] = f2b((vB[nt][i] - mB)*rB*ls + lb);
      }
    }
  }

  // a-frags: rows written by this same wave -> readable without barrier
  bf16x8 aA[4], aB[4];
#pragma unroll
  for (int kt = 0; kt < 4; ++kt){
    aA[kt] = *(const bf16x8*)&sXp[(wv*16 + lrow)*136 + kt*32 + q*8];
    aB[kt] = *(const bf16x8*)&sXp[8704 + (wv*16 + lrow)*136 + kt*32 + q*8];
  }
  __syncthreads();   // all waves done with sX before W staging overwrites it

  // per-thread W-tile global srcs (nt advance: W1 part +8192, W2 part +64)
  const u16* wsrc[8];
#pragma unroll
  for (int r = 0; r < 8; ++r){
    int c = r*4 + wv;
    if (c < 16){
      int j = c >> 2, kt = c & 3;
      wsrc[r] = W1T + (size_t)(j*16 + lrow)*128 + kt*32 + q*8;
    } else {
      int c2 = c - 16; int jo = c2 >> 1, kt2 = c2 & 1;
      wsrc[r] = W2T + (size_t)(jo*16 + lrow)*512 + kt2*32 + q*8;
    }
  }
  auto stage = [&](u16* buf, int nt){
#pragma unroll
    for (int r = 0; r < 8; ++r){
      int c = r*4 + wv;
      const u16* src = wsrc[r] + (c < 16 ? (size_t)nt*8192 : (size_t)nt*64);
      gld_lds16(src, buf + c*512);            // dest wave-uniform; HW adds lane*16B
    }
  };

  f32x4 accA[8], accB[8];
#pragma unroll
  for (int jo = 0; jo < 8; ++jo){ accA[jo] = (f32x4){0.f,0.f,0.f,0.f}; accB[jo] = (f32x4){0.f,0.f,0.f,0.f}; }
  u16* sHw = sH + wv*1152;

  stage(sW0, 0);
  asm volatile("s_waitcnt vmcnt(0)" ::: "memory");
  __builtin_amdgcn_s_barrier();

  auto mlpstep = [&](int nt, u16* wcur, u16* wnxt, bool do_stage){
    if (do_stage) stage(wnxt, nt+1);          // in flight under both tiles' compute
    // ---- tile A ----
#pragma unroll
    for (int js = 0; js < 4; ++js){
      f32x4 hc = {0.f,0.f,0.f,0.f};
#pragma unroll
      for (int kt = 0; kt < 4; ++kt)
        hc = MFMA16(aA[kt], *(const bf16x8*)&wcur[(js*4 + kt)*512 + lane*8], hc);
      float bv = b2f(PRM[640 + nt*64 + js*16 + lrow]);
#pragma unroll
      for (int i = 0; i < 4; ++i){
        float v = hc[i] + bv;
        float u = 0.79788456080286535588f*(v + 0.044715f*v*v*v);
        float su_ = __expf(-2.f*u);
        float gl = v * __builtin_amdgcn_rcpf(1.f + su_);
        sHw[(q*4 + i)*72 + js*16 + lrow] = (u16)(__float_as_uint(gl) >> 16);
      }
    }
#pragma unroll
    for (int kt2 = 0; kt2 < 2; ++kt2){
      bf16x8 af = *(const bf16x8*)&sHw[lrow*72 + kt2*32 + q*8];
#pragma unroll
      for (int jo = 0; jo < 8; ++jo)
        accA[jo] = MFMA16(af, *(const bf16x8*)&wcur[(16 + jo*2 + kt2)*512 + lane*8], accA[jo]);
    }
    // ---- tile B (sHw reuse: same-wave DS ordering) ----
#pragma unroll
    for (int js = 0; js < 4; ++js){
      f32x4 hc = {0.f,0.f,0.f,0.f};
#pragma unroll
      for (int kt = 0; kt < 4; ++kt)
        hc = MFMA16(aB[kt], *(const bf16x8*)&wcur[(js*4 + kt)*512 + lane*8], hc);
      float bv = b2f(PRM[640 + nt*64 + js*16 + lrow]);
#pragma unroll
      for (int i = 0; i < 4; ++i){
        float v = hc[i] + bv;
        float u = 0.79788456080286535588f*(v + 0.044715f*v*v*v);
        float su_ = __expf(-2.f*u);
        float gl = v * __builtin_amdgcn_rcpf(1.f + su_);
        sHw[(q*4 + i)*72 + js*16 + lrow] = (u16)(__float_as_uint(gl) >> 16);
      }
    }
#pragma unroll
    for (int kt2 = 0; kt2 < 2; ++kt2){
      bf16x8 af = *(const bf16x8*)&sHw[lrow*72 + kt2*32 + q*8];
#pragma unroll
      for (int jo = 0; jo < 8; ++jo)
        accB[jo] = MFMA16(af, *(const bf16x8*)&wcur[(16 + jo*2 + kt2)*512 + lane*8], accB[jo]);
    }
    asm volatile("s_waitcnt vmcnt(0)" ::: "memory");   // staged tile landed; readers done next
    __builtin_amdgcn_s_barrier();
  };

  for (int nt2 = 0; nt2 < 4; ++nt2){
    mlpstep(2*nt2,     sW0, sW1, true);
    mlpstep(2*nt2 + 1, sW1, sW0, nt2 < 3);
  }

  // ---- epilogue: out = (acc + b2)*gamma + x  (both tiles) ----
  size_t rowA0 = ((size_t)(b*16 + t2))*3136 + hw0 + wv*16 + q*4;
  size_t rowB0 = rowA0 + (size_t)8*3136;
#pragma unroll
  for (int jo = 0; jo < 8; ++jo){
    int c = jo*16 + lrow;
    float bv  = b2f(PRM[1152 + c]);
    float gmv = b2f(PRM[1280 + c]);
#pragma unroll
    for (int i = 0; i < 4; ++i){
      size_t rA = rowA0 + i, rB = rowB0 + i;
      float yA = accA[jo][i] + bv, yB = accB[jo][i] + bv;
      if (f32io){
        float resA = ((const float*)xraw)[rA*128 + c];
        float resB = ((const float*)xraw)[rB*128 + c];
        ((float*)outv)[rA*128 + c] = yA*gmv + resA;
        ((float*)outv)[rB*128 + c] = yB*gmv + resB;
      } else {
        float resA = b2f(((const u16*)xraw)[rA*128 + c]);
        float resB = b2f(((const u16*)xraw)[rB*128 + c]);
        ((u16*)outv)[rA*128 + c] = f2b(yA*gmv + resA);
        ((u16*)outv)[rB*128 + c] = f2b(yB*gmv + resB);
      }
    }
  }
}

// ---------------- launch ----------------
extern "C" void kernel_launch(void* const* d_in, const int* in_sizes, int n_in,
                              void* d_out, int out_size, void* d_ws, size_t ws_size,
                              hipStream_t stream)
{
  const void* x   = d_in[0];
  const void* Wg  = d_in[1];
  const void* bg  = d_in[2];
  const void* Wh  = d_in[3];
  const void* bh  = d_in[4];
  const void* gk  = d_in[5];
  const void* hk  = d_in[6];
  const void* Wo  = d_in[7];
  const void* bo  = d_in[8];
  const void* lns = d_in[9];
  const void* lnb = d_in[10];
  const void* W1  = d_in[11];
  const void* b1  = d_in[12];
  const void* W2  = d_in[13];
  const void* b2  = d_in[14];
  const void* gm  = d_in[15];

  char* ws = (char*)d_ws;
  u16* GP  = (u16*)(ws + 0);              // 25,690,112 B each (f16)
  u16* HP  = (u16*)(ws + 25690112);
  u16* ELH = (u16*)(ws + 51380224);       // bf16
  u16* XB  = (u16*)(ws + 77070336);       // canonical bf16 x
  u16* WgT = (u16*)(ws + 102760448);
  u16* WhT = WgT + 16384;
  u16* WoT = WhT + 16384;
  u16* W1T = WoT + 16384;
  u16* W2T = W1T + 65536;
  unsigned* KWG = (unsigned*)(W2T + 65536);    // 31,360 u32 each (slot is 50,176)
  unsigned* KWH = KWG + 50176;
  u16* PRM = (u16*)(KWH + 50176);

  k0_prep        <<<dim3(512),  dim3(256), 0, stream>>>(x, Wg, Wh, Wo, W1, W2, gk, hk,
                                                        bg, bh, bo, lns, lnb, b1, b2, gm,
                                                        XB, WgT, WhT, WoT, W1T, W2T, KWG, KWH, PRM);
  k1_dualgemm    <<<dim3(1568), dim3(256), 0, stream>>>(XB, WgT, WhT, PRM, GP, HP);
  k2_conv_scan   <<<dim3(3136), dim3(256), 0, stream>>>(GP, HP, KWG, KWH, ELH);
  k34_gemm_ln_mlp<<<dim3(784),  dim3(256), 0, stream>>>(ELH, WoT, W1T, W2T, PRM, x, (void*)d_out);
}

// Round 5
// 398.540 us; speedup vs baseline: 1.4362x; 1.1191x over previous
//
#include <hip/hip_runtime.h>
#include <hip/hip_bf16.h>
#include <hip/hip_fp16.h>
#include <cstdint>
#include <cstddef>

typedef unsigned short u16;
typedef __attribute__((ext_vector_type(8))) short bf16x8;
typedef __attribute__((ext_vector_type(8))) _Float16 f16x8;
typedef __attribute__((ext_vector_type(4))) float f32x4;

#define MFMA16(a,b,c)  __builtin_amdgcn_mfma_f32_16x16x32_bf16((a),(b),(c),0,0,0)
#define MFMAF16(a,b,c) __builtin_amdgcn_mfma_f32_16x16x32_f16((a),(b),(c),0,0,0)

// B=2 T=16 H=W=56 C=128  HW=3136  N=100352  HID=512
// GP/HP (f16) layout: [b][cg32][hw3136][cl4][t16]  (t contiguous, 32B per (hw,cl))
//   u16 idx = (((b*32+cg)*3136 + hw)*4 + cl)*16 + t          slab = 200704 u16/(b,cg)
// ELH (bf16) layout: (((b*32+cg)*16 + t)*3136 + hw)*4 + cl
// CIRG/CIRH (f16 MFMA B-frags of temporal circulants, taps paired 2-per-MFMA):
//   u32 idx = ((c*25 + tp)*64 + lane)*4 + uu      (16B per lane per tap-pair)

static __device__ __forceinline__ float b2f(u16 u){ return __uint_as_float(((unsigned)u)<<16); }
static __device__ __forceinline__ u16 f2b(float f){
  unsigned u = __float_as_uint(f);
  return (u16)((u + 0x7fffu + ((u>>16)&1u)) >> 16);
}
static __device__ __forceinline__ u16 f2h(float f){ return __half_as_ushort(__float2half(f)); }

union U4F { uint4 u; f16x8 h; };

// async global->LDS 16B: LDS dest = wave-uniform base + lane*16, global src per-lane
static __device__ __forceinline__ void gld_lds16(const void* g, void* l){
  __builtin_amdgcn_global_load_lds(
      (const __attribute__((address_space(1))) void*)g,
      (__attribute__((address_space(3))) void*)l, 16, 0, 0);
}

// dtype detector: sample 64 even-index u16 words of x. bf16 N(0,1) data -> exponent
// field in [100,140] essentially always; f32 -> mantissa halves, ~uniform exponent.
static __device__ __forceinline__ bool input_is_f32(const void* xp){
  const u16* u = (const u16*)xp;
  int cnt = 0;
#pragma unroll
  for (int i = 0; i < 64; ++i){
    unsigned e = (u[2*i] >> 7) & 0xFF;
    cnt += (e >= 100 && e <= 140) ? 1 : 0;
  }
  return cnt < 32;
}

static __device__ __forceinline__ u16 ldb(const void* p, int i, bool f32){
  return f32 ? f2b(((const float*)p)[i]) : ((const u16*)p)[i];
}
static __device__ __forceinline__ float ldf(const void* p, int i, bool f32){
  return f32 ? ((const float*)p)[i] : b2f(((const u16*)p)[i]);
}

// ---------------- K0: canonicalize inputs (+ transposes + circulant B-frag build) ----------------
__global__ __launch_bounds__(256) void k0_prep(
    const void* __restrict__ x,
    const void* __restrict__ Wg, const void* __restrict__ Wh, const void* __restrict__ Wo,
    const void* __restrict__ W1, const void* __restrict__ W2,
    const void* __restrict__ gk, const void* __restrict__ hk,
    const void* __restrict__ bg, const void* __restrict__ bh, const void* __restrict__ bo,
    const void* __restrict__ lns, const void* __restrict__ lnb,
    const void* __restrict__ b1, const void* __restrict__ b2, const void* __restrict__ gm,
    u16* __restrict__ XB,
    u16* __restrict__ WgT, u16* __restrict__ WhT, u16* __restrict__ WoT,
    u16* __restrict__ W1T, u16* __restrict__ W2T,
    unsigned* __restrict__ CIRG, unsigned* __restrict__ CIRH, u16* __restrict__ PRM)
{
  const bool f32 = input_is_f32(x);
  int tid = blockIdx.x*blockDim.x + threadIdx.x;
  int np  = gridDim.x*blockDim.x;

  // x -> XB (bf16), 2 elements per u32 store
  if (f32){
    const float* xf = (const float*)x;
    for (int p = tid; p < 6422528; p += np){
      unsigned v = (unsigned)f2b(xf[2*p]) | ((unsigned)f2b(xf[2*p+1]) << 16);
      ((unsigned*)XB)[p] = v;
    }
  } else {
    const unsigned* xu = (const unsigned*)x;
    for (int p = tid; p < 6422528; p += np) ((unsigned*)XB)[p] = xu[p];
  }

  for (int p = tid; p < 16384; p += np){           // 128x128 transposes
    int n = p>>7, k = p&127;
    WgT[p] = ldb(Wg, k*128+n, f32);
    WhT[p] = ldb(Wh, k*128+n, f32);
    WoT[p] = ldb(Wo, k*128+n, f32);
  }
  for (int p = tid; p < 65536; p += np){           // W1 (128,512) -> W1T (512,128)
    int n = p>>7, k = p&127;
    W1T[p] = ldb(W1, k*512+n, f32);
  }
  for (int p = tid; p < 65536; p += np){           // W2 (512,128) -> W2T (128,512)
    int n = p>>9, k = p&511;
    W2T[p] = ldb(W2, k*128+n, f32);
  }

  // circulant B-fragments for mfma_f32_16x16x32_f16:
  //   B[k][n]: n = t_out (lane&15), k = (lane>>4)*8 + jj; tap-pair tp: spatial tap
  //   tapA = 2tp (k<16), tapB = 2tp+1 (k>=16, zero-padded at tp=24).
  //   B[k][n] = w[c][tap][(n - t_in + 2) mod 16] if that temporal idx < 5 else 0,
  //   with t_in = (k&15). gate/hidden kernel layout (C,5,7,7): w = gk[c*245 + i*49 + tap]
  for (int p = tid; p < 819200; p += np){
    int uu = p & 3;
    int lane = (p >> 2) & 63;
    int tpc = p >> 8;                 // c*25 + tp
    int c = tpc / 25, tp = tpc - c*25;
    int qq = lane >> 4, nn = lane & 15;
    int tap = 2*tp + (qq >> 1);
    unsigned vg = 0, vh = 0;
    if (tap < 49){
      int kk = ((qq & 1) << 3) + uu*2;          // t_in of low f16
      int i0 = (nn - kk + 2) & 15;
      int i1 = (nn - kk + 1) & 15;              // t_in + 1
      unsigned g0 = (i0 < 5) ? (unsigned)f2h(ldf(gk, c*245 + i0*49 + tap, f32)) : 0u;
      unsigned h0 = (i0 < 5) ? (unsigned)f2h(ldf(hk, c*245 + i0*49 + tap, f32)) : 0u;
      unsigned g1 = (i1 < 5) ? (unsigned)f2h(ldf(gk, c*245 + i1*49 + tap, f32)) : 0u;
      unsigned h1 = (i1 < 5) ? (unsigned)f2h(ldf(hk, c*245 + i1*49 + tap, f32)) : 0u;
      vg = g0 | (g1 << 16);
      vh = h0 | (h1 << 16);
    }
    CIRG[p] = vg; CIRH[p] = vh;
  }

  // param block (bf16): bg@0 bh@128 bo@256 lns@384 lnb@512 b1@640 b2@1152 gamma@1280
  for (int p = tid; p < 1408; p += np){
    const void* src; int off;
    if      (p < 128)  { src = bg;  off = p; }
    else if (p < 256)  { src = bh;  off = p-128; }
    else if (p < 384)  { src = bo;  off = p-256; }
    else if (p < 512)  { src = lns; off = p-384; }
    else if (p < 640)  { src = lnb; off = p-512; }
    else if (p < 1152) { src = b1;  off = p-640; }
    else if (p < 1280) { src = b2;  off = p-1152; }
    else               { src = gm;  off = p-1280; }
    PRM[p] = ldb(src, off, f32);
  }
}

// ---------------- K1: dual GEMM  gate = x@Wg+bg, hidden = x@Wh+bh (f16 out, t-contiguous) ----------------
__global__ __launch_bounds__(256) void k1_dualgemm(
    const u16* __restrict__ XB, const u16* __restrict__ WgT, const u16* __restrict__ WhT,
    const u16* __restrict__ PRM,
    u16* __restrict__ GP, u16* __restrict__ HP)
{
  int bid = blockIdx.x;                  // 1568 = 2b * 784 hw-groups
  int b = bid / 784; int hw = (bid % 784)*4 + (threadIdx.x >> 6);
  int lane = threadIdx.x & 63;
  int lrow = lane & 15, q = lane >> 4;

  bf16x8 a[4];   // A row (in-tile) = lrow = t; k-cols q*8 + kt*32
  const u16* xr = XB + ((size_t)(b*16 + lrow)*3136 + hw)*128 + q*8;
#pragma unroll
  for (int kt = 0; kt < 4; ++kt) a[kt] = *(const bf16x8*)(xr + kt*32);

#pragma unroll
  for (int mat = 0; mat < 2; ++mat){
    const u16* WT  = mat ? WhT : WgT;
    const u16* bia = PRM + (mat ? 128 : 0);
    u16* out       = mat ? HP  : GP;
#pragma unroll
    for (int nt = 0; nt < 8; ++nt){
      f32x4 acc = {0.f,0.f,0.f,0.f};
      const u16* wr = WT + (nt*16 + lrow)*128 + q*8;
#pragma unroll
      for (int kt = 0; kt < 4; ++kt){
        bf16x8 bfr = *(const bf16x8*)(wr + kt*32);
        acc = MFMA16(a[kt], bfr, acc);
      }
      int c = nt*16 + lrow;              // C col = output channel
      float bv = b2f(bia[c]);
      size_t base = (((size_t)(b*32 + (c>>2))*3136 + hw)*4 + (c&3))*16 + q*4;
      ushort4 pk;
      pk.x = f2h(acc[0] + bv); pk.y = f2h(acc[1] + bv);
      pk.z = f2h(acc[2] + bv); pk.w = f2h(acc[3] + bv);
      *(ushort4*)(out + base) = pk;      // t = q*4 .. q*4+3
    }
  }
}

// ---------------- K2: circular 5x7x7 depthwise conv via MFMA circulants + linear scan ----------------
// Wave = one channel. su layout: per-channel planes, byte = cl*6272 + pos*32 + half*16
// (pos = hh*14+ww over the 14x14 halo tile; half selects t0-7/t8-15; linear for gld_lds).
// Conv: out[64sp,16t] = sum_tap X_tap[64sp,16t] @ C_tap[16,16]; taps paired (K=32 MFMA).
// A-frag: lane(q,lrow): row = m*16+lrow -> (h = m*2+(lrow>>3), w = lrow&7) shifted by tap(q>>1),
//         16B ds_read at half=q&1. C/D: col = t_out = lrow, rows q*4+i.
// Scan (t across 16-lane groups, linear space): h_t = f*h_{t-1} + v; f = sigmoid(-g),
// v = sigmoid(g)*(hconv^2 + 1e-6). 4-step shfl_up Hillis-Steele.
__global__ __launch_bounds__(256, 5) void k2_conv_scan(
    const u16* __restrict__ GP, const u16* __restrict__ HP,
    const u16* __restrict__ CIRG, const u16* __restrict__ CIRH,
    u16* __restrict__ ELH)
{
  __shared__ __align__(16) unsigned su[6272];   // 25,088 B

  int bid = blockIdx.x;                    // 3136 = 2 * 32 * 49
  int b = bid / 1568; int rr = bid - b*1568;
  int cg = rr / 49; int s = rr % 49;
  int th = s / 7, tw = s % 7;
  int tid = threadIdx.x;
  int h0g = th*8, w0g = tw*8;
  size_t tb = (size_t)(b*32 + cg)*200704;  // u16 slab base (GP/HP/ELH identical value)

  int wv = tid >> 6, lane = tid & 63;
  int q = lane >> 4, lrow = lane & 15;
  int hb = lrow >> 3, wb = lrow & 7;       // spatial of A-row at m=0: h=hb, w=wb

  int cu = __builtin_amdgcn_readfirstlane(cg*4 + wv);
  const u16* cirg = CIRG + (size_t)cu*12800;   // 25 tp * 64 lane * 8 u16
  const u16* cirh = CIRH + (size_t)cu*12800;

  // ---- staging chunk offsets: chunk ci = cl*392 + pos*2 + half  (LDS addr = ci*16, linear) ----
  unsigned soff[7]; bool sval[7];
#pragma unroll
  for (int ss = 0; ss < 7; ++ss){
    int ci = ss*256 + tid;
    sval[ss] = (ci < 1568);
    int clc = ci / 392;
    int rem = ci - clc*392;
    int pos = rem >> 1, half = rem & 1;
    int hh = pos / 14, ww = pos - hh*14;
    int hg = h0g + hh - 3; if (hg < 0) hg += 56; else if (hg >= 56) hg -= 56;
    int wg = w0g + ww - 3; if (wg < 0) wg += 56; else if (wg >= 56) wg -= 56;
    soff[ss] = (unsigned)((hg*56 + wg)*128 + clc*32 + half*16);
  }
  const char* gpb = (const char*)(GP + tb);
  const char* hpb = (const char*)(HP + tb);

  auto stagepass = [&](const char* Pb){
#pragma unroll
    for (int ss = 0; ss < 7; ++ss){
      if (sval[ss])
        gld_lds16(Pb + soff[ss], (char*)su + (ss*256 + wv*64)*16);
    }
  };

  auto convpass = [&](const u16* cir, f32x4* acc){
#pragma unroll
    for (int m = 0; m < 4; ++m) acc[m] = (f32x4){0.f,0.f,0.f,0.f};
    U4F bq0, bq1, bq2;
    bq0.u = *(const uint4*)(cir + 0*512 + lane*8);
    bq1.u = *(const uint4*)(cir + 1*512 + lane*8);
    bq2.u = *(const uint4*)(cir + 2*512 + lane*8);
    const int base_cl = wv*6272;
#pragma unroll
    for (int tp = 0; tp < 25; ++tp){
      const int tA = 2*tp;
      const int tB = (2*tp + 1 > 48) ? 48 : 2*tp + 1;
      const int dhA = 6 - tA/7, dwA = 6 - tA%7;
      const int dhB = 6 - tB/7, dwB = 6 - tB%7;
      int dh = (q >= 2) ? dhB : dhA;
      int dw = (q >= 2) ? dwB : dwA;
      const char* sp = (const char*)su +
          (base_cl + ((hb + dh)*14 + (wb + dw))*32 + (q & 1)*16);
      U4F a0, a1, a2, a3;
      a0.u = *(const uint4*)(sp);
      a1.u = *(const uint4*)(sp + 896);    // m=1: h += 2 -> pos += 28
      a2.u = *(const uint4*)(sp + 1792);
      a3.u = *(const uint4*)(sp + 2688);
      f16x8 bb = (tp % 3 == 0) ? bq0.h : (tp % 3 == 1) ? bq1.h : bq2.h;
      acc[0] = MFMAF16(a0.h, bb, acc[0]);
      acc[1] = MFMAF16(a1.h, bb, acc[1]);
      acc[2] = MFMAF16(a2.h, bb, acc[2]);
      acc[3] = MFMAF16(a3.h, bb, acc[3]);
      if (tp + 3 < 25){
        uint4 nb = *(const uint4*)(cir + (tp+3)*512 + lane*8);
        if (tp % 3 == 0) bq0.u = nb; else if (tp % 3 == 1) bq1.u = nb; else bq2.u = nb;
      }
    }
  };

  f32x4 accG[4], accH[4];
  stagepass(gpb);
  __syncthreads();          // gld_lds data resident
  convpass(cirg, accG);
  __syncthreads();          // conv reads done before restage overwrites
  stagepass(hpb);
  __syncthreads();
  convpass(cirh, accH);

  // ---- pointwise (linear-space) ----
  float fv[16], vv[16];
#pragma unroll
  for (int e = 0; e < 16; ++e){
    float g  = accG[e>>2][e&3];
    float hc = accH[e>>2][e&3];
    float eg = __expf(g);
    float fr = __builtin_amdgcn_rcpf(1.f + eg);   // 1 - z = sigmoid(-g)
    float zz = 1.f - fr;                          // z = sigmoid(g), inf-safe
    fv[e] = fr;
    vv[e] = (hc*hc + 1e-6f) * zz;
  }
  // ---- inclusive scan over t (= lrow) within 16-lane groups ----
#pragma unroll
  for (int d = 1; d < 16; d <<= 1){
    bool ok = (lrow >= d);
#pragma unroll
    for (int e = 0; e < 16; ++e){
      float Lf = __shfl_up(fv[e], (unsigned)d, 16);
      float Lv = __shfl_up(vv[e], (unsigned)d, 16);
      Lf = ok ? Lf : 1.f;
      Lv = ok ? Lv : 0.f;
      vv[e] = fmaf(fv[e], Lv, vv[e]);
      fv[e] = fv[e] * Lf;
    }
  }
  // ---- store h = vv (bf16) ----
  size_t ob = tb + (size_t)lrow*12544 + (size_t)(h0g*56 + w0g)*4 + wv;
#pragma unroll
  for (int e = 0; e < 16; ++e){
    int r = (e>>2)*16 + q*4 + (e&3);
    ELH[ob + (size_t)((r>>3)*56 + (r&7))*4] = f2b(vv[e]);
  }
}

// ---------------- K34: M=128 (row-tiles t2 and t2+8), gld_lds double-buffered W staging ----------------
__global__ __launch_bounds__(256, 2) void k34_gemm_ln_mlp(
    const u16* __restrict__ ELH, const u16* __restrict__ WoT,
    const u16* __restrict__ W1T, const u16* __restrict__ W2T,
    const u16* __restrict__ PRM,
    const void* __restrict__ xraw, void* __restrict__ outv)
{
  __shared__ __align__(16) u16 smem[37376];   // 74,752 B -> 2 blocks/CU
  u16* sW0 = smem;               // 16384 u16 (32 KB)
  u16* sW1 = smem + 16384;       // 16384 u16
  u16* sXp = smem;               // 2*64*136 = 17408 u16 (phase A only; dead before staging)
  u16* sH  = smem + 32768;       // 4 waves * 1152 u16

  int bid = blockIdx.x;          // 784 = 2b * 8t2 * 49s
  int b = bid / 392; int rem = bid - b*392;
  int t2 = rem / 49; int s2 = rem - t2*49;
  int hw0 = s2 * 64;
  int tid = threadIdx.x;
  int wv = tid >> 6, lane = tid & 63;
  int lrow = lane & 15, q = lane >> 4;
  const bool f32io = input_is_f32(xraw);

  // ---- phase A: ssm_out = elh@Wo + bo, LayerNorm -> sX (tiles A: t2, B: t2+8) ----
  {
    int hw = hw0 + wv*16 + lrow;
    size_t tbA = ((size_t)(b*512) + t2)*3136;      // ((b*32+0)*16 + t2)*3136
    size_t tbB = tbA + (size_t)8*3136;
    union Cvt { uint4 u; bf16x8 v; };
    bf16x8 eA[4], eB[4];
#pragma unroll
    for (int kt = 0; kt < 4; ++kt){
      int cg0 = kt*8 + q*2;
      size_t eoA = (tbA + (size_t)cg0*50176 + hw)*4;
      size_t eoB = (tbB + (size_t)cg0*50176 + hw)*4;
      uint2 lo = *(const uint2*)(ELH + eoA);
      uint2 hi = *(const uint2*)(ELH + eoA + (size_t)50176*4);
      Cvt c1; c1.u = make_uint4(lo.x, lo.y, hi.x, hi.y); eA[kt] = c1.v;
      uint2 lo2 = *(const uint2*)(ELH + eoB);
      uint2 hi2 = *(const uint2*)(ELH + eoB + (size_t)50176*4);
      Cvt c2; c2.u = make_uint4(lo2.x, lo2.y, hi2.x, hi2.y); eB[kt] = c2.v;
    }

    float vA[8][4], vB[8][4];
#pragma unroll
    for (int nt = 0; nt < 8; ++nt){
      f32x4 aacc = {0.f,0.f,0.f,0.f}, bacc = {0.f,0.f,0.f,0.f};
      const u16* wr = WoT + (nt*16 + lrow)*128 + q*8;
#pragma unroll
      for (int kt = 0; kt < 4; ++kt){
        bf16x8 bfr = *(const bf16x8*)(wr + kt*32);
        aacc = MFMA16(eA[kt], bfr, aacc);
        bacc = MFMA16(eB[kt], bfr, bacc);
      }
      float bv = b2f(PRM[256 + nt*16 + lrow]);
#pragma unroll
      for (int i = 0; i < 4; ++i){ vA[nt][i] = aacc[i] + bv; vB[nt][i] = bacc[i] + bv; }
    }

#pragma unroll
    for (int i = 0; i < 4; ++i){
      float smA=0.f, sqA=0.f, smB=0.f, sqB=0.f;
#pragma unroll
      for (int nt = 0; nt < 8; ++nt){
        float a_ = vA[nt][i]; smA += a_; sqA = fmaf(a_, a_, sqA);
        float b_ = vB[nt][i]; smB += b_; sqB = fmaf(b_, b_, sqB);
      }
#pragma unroll
      for (int m = 1; m < 16; m <<= 1){
        smA += __shfl_xor(smA, m, 64); sqA += __shfl_xor(sqA, m, 64);
        smB += __shfl_xor(smB, m, 64); sqB += __shfl_xor(sqB, m, 64);
      }
      float mA = smA*(1.f/128.f), rA = rsqrtf(sqA*(1.f/128.f) - mA*mA + 1e-6f);
      float mB = smB*(1.f/128.f), rB = rsqrtf(sqB*(1.f/128.f) - mB*mB + 1e-6f);
      int r = wv*16 + q*4 + i;
#pragma unroll
      for (int nt = 0; nt < 8; ++nt){
        int c = nt*16 + lrow;
        float ls = b2f(PRM[384 + c]), lb = b2f(PRM[512 + c]);
        sXp[r*136 + c]        = f2b((vA[nt][i] - mA)*rA*ls + lb);
        sXp[8704 + r*136 + c] = f2b((vB[nt][i] - mB)*rB*ls + lb);
      }
    }
  }

  // a-frags: rows written by this same wave -> readable without barrier
  bf16x8 aA[4], aB[4];
#pragma unroll
  for (int kt = 0; kt < 4; ++kt){
    aA[kt] = *(const bf16x8*)&sXp[(wv*16 + lrow)*136 + kt*32 + q*8];
    aB[kt] = *(const bf16x8*)&sXp[8704 + (wv*16 + lrow)*136 + kt*32 + q*8];
  }
  __syncthreads();   // all waves done with sX before W staging overwrites it

  // per-thread W-tile global srcs (nt advance: W1 part +8192, W2 part +64)
  const u16* wsrc[8];
#pragma unroll
  for (int r = 0; r < 8; ++r){
    int c = r*4 + wv;
    if (c < 16){
      int j = c >> 2, kt = c & 3;
      wsrc[r] = W1T + (size_t)(j*16 + lrow)*128 + kt*32 + q*8;
    } else {
      int c2 = c - 16; int jo = c2 >> 1, kt2 = c2 & 1;
      wsrc[r] = W2T + (size_t)(jo*16 + lrow)*512 + kt2*32 + q*8;
    }
  }
  auto stage = [&](u16* buf, int nt){
#pragma unroll
    for (int r = 0; r < 8; ++r){
      int c = r*4 + wv;
      const u16* src = wsrc[r] + (c < 16 ? (size_t)nt*8192 : (size_t)nt*64);
      gld_lds16(src, buf + c*512);            // dest wave-uniform; HW adds lane*16B
    }
  };

  f32x4 accA[8], accB[8];
#pragma unroll
  for (int jo = 0; jo < 8; ++jo){ accA[jo] = (f32x4){0.f,0.f,0.f,0.f}; accB[jo] = (f32x4){0.f,0.f,0.f,0.f}; }
  u16* sHw = sH + wv*1152;

  stage(sW0, 0);
  asm volatile("s_waitcnt vmcnt(0)" ::: "memory");
  __builtin_amdgcn_s_barrier();

  auto mlpstep = [&](int nt, u16* wcur, u16* wnxt, bool do_stage){
    if (do_stage) stage(wnxt, nt+1);          // in flight under both tiles' compute
    // ---- tile A ----
#pragma unroll
    for (int js = 0; js < 4; ++js){
      f32x4 hc = {0.f,0.f,0.f,0.f};
#pragma unroll
      for (int kt = 0; kt < 4; ++kt)
        hc = MFMA16(aA[kt], *(const bf16x8*)&wcur[(js*4 + kt)*512 + lane*8], hc);
      float bv = b2f(PRM[640 + nt*64 + js*16 + lrow]);
#pragma unroll
      for (int i = 0; i < 4; ++i){
        float v = hc[i] + bv;
        float u = 0.79788456080286535588f*(v + 0.044715f*v*v*v);
        float su_ = __expf(-2.f*u);
        float gl = v * __builtin_amdgcn_rcpf(1.f + su_);
        sHw[(q*4 + i)*72 + js*16 + lrow] = (u16)(__float_as_uint(gl) >> 16);
      }
    }
#pragma unroll
    for (int kt2 = 0; kt2 < 2; ++kt2){
      bf16x8 af = *(const bf16x8*)&sHw[lrow*72 + kt2*32 + q*8];
#pragma unroll
      for (int jo = 0; jo < 8; ++jo)
        accA[jo] = MFMA16(af, *(const bf16x8*)&wcur[(16 + jo*2 + kt2)*512 + lane*8], accA[jo]);
    }
    // ---- tile B (sHw reuse: same-wave DS ordering) ----
#pragma unroll
    for (int js = 0; js < 4; ++js){
      f32x4 hc = {0.f,0.f,0.f,0.f};
#pragma unroll
      for (int kt = 0; kt < 4; ++kt)
        hc = MFMA16(aB[kt], *(const bf16x8*)&wcur[(js*4 + kt)*512 + lane*8], hc);
      float bv = b2f(PRM[640 + nt*64 + js*16 + lrow]);
#pragma unroll
      for (int i = 0; i < 4; ++i){
        float v = hc[i] + bv;
        float u = 0.79788456080286535588f*(v + 0.044715f*v*v*v);
        float su_ = __expf(-2.f*u);
        float gl = v * __builtin_amdgcn_rcpf(1.f + su_);
        sHw[(q*4 + i)*72 + js*16 + lrow] = (u16)(__float_as_uint(gl) >> 16);
      }
    }
#pragma unroll
    for (int kt2 = 0; kt2 < 2; ++kt2){
      bf16x8 af = *(const bf16x8*)&sHw[lrow*72 + kt2*32 + q*8];
#pragma unroll
      for (int jo = 0; jo < 8; ++jo)
        accB[jo] = MFMA16(af, *(const bf16x8*)&wcur[(16 + jo*2 + kt2)*512 + lane*8], accB[jo]);
    }
    asm volatile("s_waitcnt vmcnt(0)" ::: "memory");   // staged tile landed; readers done next
    __builtin_amdgcn_s_barrier();
  };

  for (int nt2 = 0; nt2 < 4; ++nt2){
    mlpstep(2*nt2,     sW0, sW1, true);
    mlpstep(2*nt2 + 1, sW1, sW0, nt2 < 3);
  }

  // ---- epilogue: out = (acc + b2)*gamma + x  (both tiles) ----
  size_t rowA0 = ((size_t)(b*16 + t2))*3136 + hw0 + wv*16 + q*4;
  size_t rowB0 = rowA0 + (size_t)8*3136;
#pragma unroll
  for (int jo = 0; jo < 8; ++jo){
    int c = jo*16 + lrow;
    float bv  = b2f(PRM[1152 + c]);
    float gmv = b2f(PRM[1280 + c]);
#pragma unroll
    for (int i = 0; i < 4; ++i){
      size_t rA = rowA0 + i, rB = rowB0 + i;
      float yA = accA[jo][i] + bv, yB = accB[jo][i] + bv;
      if (f32io){
        float resA = ((const float*)xraw)[rA*128 + c];
        float resB = ((const float*)xraw)[rB*128 + c];
        ((float*)outv)[rA*128 + c] = yA*gmv + resA;
        ((float*)outv)[rB*128 + c] = yB*gmv + resB;
      } else {
        float resA = b2f(((const u16*)xraw)[rA*128 + c]);
        float resB = b2f(((const u16*)xraw)[rB*128 + c]);
        ((u16*)outv)[rA*128 + c] = f2b(yA*gmv + resA);
        ((u16*)outv)[rB*128 + c] = f2b(yB*gmv + resB);
      }
    }
  }
}

// ---------------- launch ----------------
extern "C" void kernel_launch(void* const* d_in, const int* in_sizes, int n_in,
                              void* d_out, int out_size, void* d_ws, size_t ws_size,
                              hipStream_t stream)
{
  const void* x   = d_in[0];
  const void* Wg  = d_in[1];
  const void* bg  = d_in[2];
  const void* Wh  = d_in[3];
  const void* bh  = d_in[4];
  const void* gk  = d_in[5];
  const void* hk  = d_in[6];
  const void* Wo  = d_in[7];
  const void* bo  = d_in[8];
  const void* lns = d_in[9];
  const void* lnb = d_in[10];
  const void* W1  = d_in[11];
  const void* b1  = d_in[12];
  const void* W2  = d_in[13];
  const void* b2  = d_in[14];
  const void* gm  = d_in[15];

  char* ws = (char*)d_ws;
  u16* GP  = (u16*)(ws + 0);              // 25,690,112 B each (f16)
  u16* HP  = (u16*)(ws + 25690112);
  u16* ELH = (u16*)(ws + 51380224);       // bf16
  u16* XB  = (u16*)(ws + 77070336);       // canonical bf16 x
  u16* WgT = (u16*)(ws + 102760448);
  u16* WhT = WgT + 16384;
  u16* WoT = WhT + 16384;
  u16* W1T = WoT + 16384;
  u16* W2T = W1T + 65536;
  unsigned* CIRG = (unsigned*)(W2T + 65536);   // 819,200 u32 = 3,276,800 B each
  unsigned* CIRH = CIRG + 819200;
  u16* PRM = (u16*)(CIRH + 819200);

  k0_prep        <<<dim3(512),  dim3(256), 0, stream>>>(x, Wg, Wh, Wo, W1, W2, gk, hk,
                                                        bg, bh, bo, lns, lnb, b1, b2, gm,
                                                        XB, WgT, WhT, WoT, W1T, W2T, CIRG, CIRH, PRM);
  k1_dualgemm    <<<dim3(1568), dim3(256), 0, stream>>>(XB, WgT, WhT, PRM, GP, HP);
  k2_conv_scan   <<<dim3(3136), dim3(256), 0, stream>>>(GP, HP, (const u16*)CIRG, (const u16*)CIRH, ELH);
  k34_gemm_ln_mlp<<<dim3(784),  dim3(256), 0, stream>>>(ELH, WoT, W1T, W2T, PRM, x, (void*)d_out);
}